// Round 1
// baseline (460.530 us; speedup 1.0000x reference)
//
#include <hip/hip_runtime.h>

#define NNODES 50000
#define NEDGES 800000

// ---- order-preserving float<->uint encoding for atomicMax on floats ----
__device__ inline unsigned fenc(float f) {
    unsigned u = __float_as_uint(f);
    return (u & 0x80000000u) ? ~u : (u | 0x80000000u);
}
__device__ inline float fdec(unsigned u) {
    return (u & 0x80000000u) ? __uint_as_float(u ^ 0x80000000u) : __uint_as_float(~u);
}

__device__ inline float wred64(float v) {
    #pragma unroll
    for (int off = 32; off; off >>= 1) v += __shfl_down(v, off, 64);
    return v;
}

// ---- zero the accumulator region + output ----
__global__ void k_init(float* __restrict__ zbuf, int zn, float* __restrict__ dout) {
    int i = blockIdx.x * blockDim.x + threadIdx.x;
    int stride = gridDim.x * blockDim.x;
    for (int k = i; k < zn; k += stride) zbuf[k] = 0.f;
    for (int k = i; k < NNODES; k += stride) dout[k] = 0.f;
}

// ---- h0 = x @ W0  (N x 128) (128 x 128); 16 rows per 256-thread block ----
__global__ __launch_bounds__(256) void k_gemm0(const float* __restrict__ x,
                                               const float* __restrict__ W,
                                               float* __restrict__ h0) {
    __shared__ float xs[16 * 128];
    int n0 = blockIdx.x * 16;
    int t = threadIdx.x;
    for (int i = t; i < 16 * 128; i += 256) {
        int r = i >> 7, c = i & 127;
        int n = n0 + r;
        xs[i] = (n < NNODES) ? x[n * 128 + c] : 0.f;
    }
    __syncthreads();
    int j = t & 127;     // output column
    int rr = t >> 7;     // 0..1
    float acc[8];
    #pragma unroll
    for (int i = 0; i < 8; i++) acc[i] = 0.f;
    for (int k = 0; k < 128; k++) {
        float w = W[k * 128 + j];
        #pragma unroll
        for (int i = 0; i < 8; i++) acc[i] += xs[(rr + 2 * i) * 128 + k] * w;
    }
    #pragma unroll
    for (int i = 0; i < 8; i++) {
        int n = n0 + rr + 2 * i;
        if (n < NNODES) h0[n * 128 + j] = acc[i];
    }
}

// ---- per-node attention dots for layer 0: ar[n,h], ac[n,h] ----
__global__ __launch_bounds__(256) void k_attn0(const float* __restrict__ h0,
                                               const float* __restrict__ attn0,
                                               float* __restrict__ ar,
                                               float* __restrict__ ac) {
    int gt = blockIdx.x * blockDim.x + threadIdx.x;
    int n = gt >> 6, lane = gt & 63;
    if (n >= NNODES) return;
    float v0 = h0[n * 128 + lane];        // head 0, channel lane
    float v1 = h0[n * 128 + 64 + lane];   // head 1, channel lane
    float r0 = v0 * attn0[lane];
    float c0 = v0 * attn0[64 + lane];
    float r1 = v1 * attn0[128 + lane];
    float c1 = v1 * attn0[192 + lane];
    r0 = wred64(r0); c0 = wred64(c0); r1 = wred64(r1); c1 = wred64(c1);
    if (lane == 0) {
        ar[n * 2] = r0; ac[n * 2] = c0;
        ar[n * 2 + 1] = r1; ac[n * 2 + 1] = c1;
    }
}

// ---- layer 0: alpha = lrelu(ar[row]+ac[col]); segment max ----
__global__ __launch_bounds__(256) void k_alpha0(const int* __restrict__ ei,
                                                const float* __restrict__ ar,
                                                const float* __restrict__ ac,
                                                float* __restrict__ alpha,
                                                unsigned* __restrict__ m) {
    int tid = blockIdx.x * blockDim.x + threadIdx.x;
    if (tid >= NEDGES * 2) return;
    int e = tid >> 1, h = tid & 1;
    int row = ei[e], col = ei[NEDGES + e];
    float a = ar[row * 2 + h] + ac[col * 2 + h];
    a = a > 0.f ? a : 0.2f * a;
    alpha[tid] = a;
    atomicMax(&m[row * 2 + h], fenc(a));
}

// ---- shared: ex = exp(alpha - m[row]); segment sum (in-place on alpha) ----
__global__ __launch_bounds__(256) void k_expsum(const int* __restrict__ ei,
                                                float* __restrict__ alpha,
                                                const unsigned* __restrict__ m,
                                                float* __restrict__ s) {
    int tid = blockIdx.x * blockDim.x + threadIdx.x;
    if (tid >= NEDGES * 2) return;
    int e = tid >> 1, h = tid & 1;
    int row = ei[e];
    float ex = expf(alpha[tid] - fdec(m[row * 2 + h]));
    alpha[tid] = ex;
    atomicAdd(&s[row * 2 + h], ex);
}

// ---- layer 0 aggregation, fused with head-mean: out0[row,c] += 0.5*(p0*h0[col,c]+p1*h0[col,64+c]) ----
__global__ __launch_bounds__(256) void k_agg0(const int* __restrict__ ei,
                                              const float* __restrict__ alpha,
                                              const float* __restrict__ s,
                                              const float* __restrict__ h0,
                                              float* __restrict__ out0) {
    int tid = blockIdx.x * blockDim.x + threadIdx.x;
    int e = tid >> 6, lane = tid & 63;
    if (e >= NEDGES) return;
    int row = ei[e], col = ei[NEDGES + e];
    float p0 = alpha[e * 2] / s[row * 2];
    float p1 = alpha[e * 2 + 1] / s[row * 2 + 1];
    float v = 0.5f * (p0 * h0[col * 128 + lane] + p1 * h0[col * 128 + 64 + lane]);
    atomicAdd(&out0[row * 64 + lane], v);
}

// ---- layer 1 node transform: h1 = relu(out0) @ W1  -> [N,2] ----
__global__ __launch_bounds__(256) void k_node1(const float* __restrict__ out0,
                                               const float* __restrict__ W1,
                                               float* __restrict__ h1) {
    int gt = blockIdx.x * blockDim.x + threadIdx.x;
    int n = gt >> 6, lane = gt & 63;
    if (n >= NNODES) return;
    float r = out0[n * 64 + lane];
    r = r > 0.f ? r : 0.f;
    float a = r * W1[lane * 2];
    float b = r * W1[lane * 2 + 1];
    a = wred64(a); b = wred64(b);
    if (lane == 0) { h1[n * 2] = a; h1[n * 2 + 1] = b; }
}

// ---- layer 1: alpha = lrelu(attn1[h,0]*h1[row,h] + attn1[h,1]*h1[col,h]); segment max ----
__global__ __launch_bounds__(256) void k_alpha1(const int* __restrict__ ei,
                                                const float* __restrict__ h1,
                                                const float* __restrict__ attn1,
                                                float* __restrict__ alpha,
                                                unsigned* __restrict__ m) {
    int tid = blockIdx.x * blockDim.x + threadIdx.x;
    if (tid >= NEDGES * 2) return;
    int e = tid >> 1, h = tid & 1;
    int row = ei[e], col = ei[NEDGES + e];
    float a = attn1[h * 2] * h1[row * 2 + h] + attn1[h * 2 + 1] * h1[col * 2 + h];
    a = a > 0.f ? a : 0.2f * a;
    alpha[tid] = a;
    atomicMax(&m[row * 2 + h], fenc(a));
}

// ---- layer 1 aggregation into final output ----
__global__ __launch_bounds__(256) void k_agg1(const int* __restrict__ ei,
                                              const float* __restrict__ alpha,
                                              const float* __restrict__ s,
                                              const float* __restrict__ h1,
                                              float* __restrict__ dout) {
    int e = blockIdx.x * blockDim.x + threadIdx.x;
    if (e >= NEDGES) return;
    int row = ei[e], col = ei[NEDGES + e];
    float p0 = alpha[e * 2] / s[row * 2];
    float p1 = alpha[e * 2 + 1] / s[row * 2 + 1];
    atomicAdd(&dout[row], 0.5f * (p0 * h1[col * 2] + p1 * h1[col * 2 + 1]));
}

extern "C" void kernel_launch(void* const* d_in, const int* in_sizes, int n_in,
                              void* d_out, int out_size, void* d_ws, size_t ws_size,
                              hipStream_t stream) {
    const float* x     = (const float*)d_in[0];
    const int*   ei    = (const int*)d_in[1];     // [2,E] int32 (row, col)
    const float* W0    = (const float*)d_in[2];
    const float* attn0 = (const float*)d_in[3];
    const float* W1    = (const float*)d_in[4];
    const float* attn1 = (const float*)d_in[5];
    float* dout = (float*)d_out;

    float* ws = (float*)d_ws;
    float* h0    = ws;                         // N*128
    float* alpha = h0 + NNODES * 128;          // E*2   (reused by both layers)
    float* zb    = alpha + NEDGES * 2;         // ---- zero region start ----
    float* out0  = zb;                         // N*64
    float* ar0   = out0 + NNODES * 64;         // N*2
    float* ac0   = ar0 + NNODES * 2;           // N*2
    unsigned* m0 = (unsigned*)(ac0 + NNODES * 2);   // N*2
    float* s0    = (float*)m0 + NNODES * 2;    // N*2
    float* h1    = s0 + NNODES * 2;            // N*2
    unsigned* m1 = (unsigned*)(h1 + NNODES * 2);    // N*2
    float* s1    = (float*)m1 + NNODES * 2;    // N*2
    int zn = (int)((s1 + NNODES * 2) - zb);

    k_init<<<1024, 256, 0, stream>>>(zb, zn, dout);
    k_gemm0<<<(NNODES + 15) / 16, 256, 0, stream>>>(x, W0, h0);
    k_attn0<<<(NNODES * 64 + 255) / 256, 256, 0, stream>>>(h0, attn0, ar0, ac0);
    k_alpha0<<<(NEDGES * 2 + 255) / 256, 256, 0, stream>>>(ei, ar0, ac0, alpha, m0);
    k_expsum<<<(NEDGES * 2 + 255) / 256, 256, 0, stream>>>(ei, alpha, m0, s0);
    k_agg0<<<(NEDGES * 64 + 255) / 256, 256, 0, stream>>>(ei, alpha, s0, h0, out0);
    k_node1<<<(NNODES * 64 + 255) / 256, 256, 0, stream>>>(out0, W1, h1);
    k_alpha1<<<(NEDGES * 2 + 255) / 256, 256, 0, stream>>>(ei, h1, attn1, alpha, m1);
    k_expsum<<<(NEDGES * 2 + 255) / 256, 256, 0, stream>>>(ei, alpha, m1, s1);
    k_agg1<<<(NEDGES + 255) / 256, 256, 0, stream>>>(ei, alpha, s1, h1, dout);
}

// Round 2
// 390.418 us; speedup vs baseline: 1.1796x; 1.1796x over previous
//
#include <hip/hip_runtime.h>
#include <math.h>

#define NNODES 50000
#define NEDGES 800000

__device__ inline float wred64(float v) {
    #pragma unroll
    for (int off = 32; off; off >>= 1) v += __shfl_down(v, off, 64);
    return v;
}

// ---- zero the degree counters ----
__global__ void k_zero(int* __restrict__ deg) {
    int i = blockIdx.x * blockDim.x + threadIdx.x;
    if (i < NNODES) deg[i] = 0;
}

// ---- CSR build: histogram ----
__global__ __launch_bounds__(256) void k_hist(const int* __restrict__ ei, int* __restrict__ deg) {
    int e = blockIdx.x * blockDim.x + threadIdx.x;
    if (e >= NEDGES) return;
    atomicAdd(&deg[ei[e]], 1);
}

// ---- CSR build: exclusive scan over 50k degrees, single block 1024 threads ----
__global__ __launch_bounds__(1024) void k_scan(const int* __restrict__ deg,
                                               int* __restrict__ rowptr,
                                               int* __restrict__ cur) {
    __shared__ int part[1024];
    const int CH = (NNODES + 1023) / 1024;   // 49
    int t = threadIdx.x;
    int base = t * CH;
    int sum = 0;
    for (int i = 0; i < CH; i++) {
        int idx = base + i;
        if (idx < NNODES) sum += deg[idx];
    }
    part[t] = sum;
    __syncthreads();
    // Hillis-Steele inclusive scan
    for (int off = 1; off < 1024; off <<= 1) {
        int v = (t >= off) ? part[t - off] : 0;
        __syncthreads();
        part[t] += v;
        __syncthreads();
    }
    int run = (t == 0) ? 0 : part[t - 1];    // exclusive prefix for this chunk
    for (int i = 0; i < CH; i++) {
        int idx = base + i;
        if (idx < NNODES) {
            rowptr[idx] = run;
            cur[idx] = run;
            run += deg[idx];
        }
    }
    if (t == 1023) rowptr[NNODES] = run;     // == NEDGES
}

// ---- CSR build: scatter cols grouped by target row ----
__global__ __launch_bounds__(256) void k_scatter(const int* __restrict__ ei,
                                                 int* __restrict__ cur,
                                                 int* __restrict__ ecol) {
    int e = blockIdx.x * blockDim.x + threadIdx.x;
    if (e >= NEDGES) return;
    int row = ei[e], col = ei[NEDGES + e];
    int p = atomicAdd(&cur[row], 1);
    ecol[p] = col;
}

// ---- h0 = x @ W0  (N x 128)(128 x 128); 16 rows per 256-thread block ----
__global__ __launch_bounds__(256) void k_gemm0(const float* __restrict__ x,
                                               const float* __restrict__ W,
                                               float* __restrict__ h0) {
    __shared__ float xs[16 * 128];
    int n0 = blockIdx.x * 16;
    int t = threadIdx.x;
    for (int i = t; i < 16 * 128; i += 256) {
        int r = i >> 7, c = i & 127;
        int n = n0 + r;
        xs[i] = (n < NNODES) ? x[n * 128 + c] : 0.f;
    }
    __syncthreads();
    int j = t & 127;
    int rr = t >> 7;
    float acc[8];
    #pragma unroll
    for (int i = 0; i < 8; i++) acc[i] = 0.f;
    for (int k = 0; k < 128; k++) {
        float w = W[k * 128 + j];
        #pragma unroll
        for (int i = 0; i < 8; i++) acc[i] += xs[(rr + 2 * i) * 128 + k] * w;
    }
    #pragma unroll
    for (int i = 0; i < 8; i++) {
        int n = n0 + rr + 2 * i;
        if (n < NNODES) h0[n * 128 + j] = acc[i];
    }
}

// ---- per-node attention dots for layer 0: ar[n,h], ac[n,h] ----
__global__ __launch_bounds__(256) void k_attn0(const float* __restrict__ h0,
                                               const float* __restrict__ attn0,
                                               float* __restrict__ ar,
                                               float* __restrict__ ac) {
    int gt = blockIdx.x * blockDim.x + threadIdx.x;
    int n = gt >> 6, lane = gt & 63;
    if (n >= NNODES) return;
    float v0 = h0[n * 128 + lane];
    float v1 = h0[n * 128 + 64 + lane];
    float r0 = v0 * attn0[lane];
    float c0 = v0 * attn0[64 + lane];
    float r1 = v1 * attn0[128 + lane];
    float c1 = v1 * attn0[192 + lane];
    r0 = wred64(r0); c0 = wred64(c0); r1 = wred64(r1); c1 = wred64(c1);
    if (lane == 0) {
        ar[n * 2] = r0; ac[n * 2] = c0;
        ar[n * 2 + 1] = r1; ac[n * 2 + 1] = c1;
    }
}

// ---- layer 0 fully fused: per-node online softmax + aggregation + head mean ----
// one wave per node; lane = channel (0..63)
__global__ __launch_bounds__(256) void k_fused0(const int* __restrict__ rowptr,
                                                const int* __restrict__ ecol,
                                                const float* __restrict__ ar,
                                                const float* __restrict__ ac,
                                                const float* __restrict__ h0,
                                                float* __restrict__ out0) {
    int gt = blockIdx.x * blockDim.x + threadIdx.x;
    int n = gt >> 6, c = gt & 63;
    if (n >= NNODES) return;
    int beg = rowptr[n], end = rowptr[n + 1];
    float arn0 = ar[n * 2], arn1 = ar[n * 2 + 1];
    float m0 = -INFINITY, s0 = 0.f, acc0 = 0.f;
    float m1 = -INFINITY, s1 = 0.f, acc1 = 0.f;
    for (int i = beg; i < end; i++) {
        int col = ecol[i];
        float2 acv = *(const float2*)&ac[col * 2];
        float v0 = h0[col * 128 + c];
        float v1 = h0[col * 128 + 64 + c];
        float a0 = arn0 + acv.x;
        float a1 = arn1 + acv.y;
        a0 = a0 > 0.f ? a0 : 0.2f * a0;
        a1 = a1 > 0.f ? a1 : 0.2f * a1;
        // branchless online softmax update (exp(-inf)=0 handles first iter)
        float nm0 = fmaxf(m0, a0);
        float r0 = __expf(m0 - nm0);
        float p0 = __expf(a0 - nm0);
        s0 = s0 * r0 + p0;
        acc0 = acc0 * r0 + p0 * v0;
        m0 = nm0;
        float nm1 = fmaxf(m1, a1);
        float r1 = __expf(m1 - nm1);
        float p1 = __expf(a1 - nm1);
        s1 = s1 * r1 + p1;
        acc1 = acc1 * r1 + p1 * v1;
        m1 = nm1;
    }
    float o = (end > beg) ? 0.5f * (acc0 / s0 + acc1 / s1) : 0.f;
    out0[n * 64 + c] = o;
}

// ---- layer 1 node transform: h1 = relu(out0) @ W1  -> [N,2] ----
__global__ __launch_bounds__(256) void k_node1(const float* __restrict__ out0,
                                               const float* __restrict__ W1,
                                               float* __restrict__ h1) {
    int gt = blockIdx.x * blockDim.x + threadIdx.x;
    int n = gt >> 6, lane = gt & 63;
    if (n >= NNODES) return;
    float r = out0[n * 64 + lane];
    r = r > 0.f ? r : 0.f;
    float a = r * W1[lane * 2];
    float b = r * W1[lane * 2 + 1];
    a = wred64(a); b = wred64(b);
    if (lane == 0) { h1[n * 2] = a; h1[n * 2 + 1] = b; }
}

// ---- layer 1 fully fused: one THREAD per node (scalar channels) ----
__global__ __launch_bounds__(256) void k_fused1(const int* __restrict__ rowptr,
                                                const int* __restrict__ ecol,
                                                const float* __restrict__ h1,
                                                const float* __restrict__ attn1,
                                                float* __restrict__ dout) {
    int n = blockIdx.x * blockDim.x + threadIdx.x;
    if (n >= NNODES) return;
    int beg = rowptr[n], end = rowptr[n + 1];
    float w00 = attn1[0], w01 = attn1[1];   // head0: row-coef, col-coef
    float w10 = attn1[2], w11 = attn1[3];   // head1
    float base0 = w00 * h1[n * 2];
    float base1 = w10 * h1[n * 2 + 1];
    float m0 = -INFINITY, s0 = 0.f, acc0 = 0.f;
    float m1 = -INFINITY, s1 = 0.f, acc1 = 0.f;
    for (int i = beg; i < end; i++) {
        int col = ecol[i];
        float2 v = *(const float2*)&h1[col * 2];
        float a0 = base0 + w01 * v.x;
        float a1 = base1 + w11 * v.y;
        a0 = a0 > 0.f ? a0 : 0.2f * a0;
        a1 = a1 > 0.f ? a1 : 0.2f * a1;
        float nm0 = fmaxf(m0, a0);
        float r0 = __expf(m0 - nm0);
        float p0 = __expf(a0 - nm0);
        s0 = s0 * r0 + p0;
        acc0 = acc0 * r0 + p0 * v.x;
        m0 = nm0;
        float nm1 = fmaxf(m1, a1);
        float r1 = __expf(m1 - nm1);
        float p1 = __expf(a1 - nm1);
        s1 = s1 * r1 + p1;
        acc1 = acc1 * r1 + p1 * v.y;
        m1 = nm1;
    }
    dout[n] = (end > beg) ? 0.5f * (acc0 / s0 + acc1 / s1) : 0.f;
}

extern "C" void kernel_launch(void* const* d_in, const int* in_sizes, int n_in,
                              void* d_out, int out_size, void* d_ws, size_t ws_size,
                              hipStream_t stream) {
    const float* x     = (const float*)d_in[0];
    const int*   ei    = (const int*)d_in[1];     // [2,E] int32 (row, col)
    const float* W0    = (const float*)d_in[2];
    const float* attn0 = (const float*)d_in[3];
    const float* W1    = (const float*)d_in[4];
    const float* attn1 = (const float*)d_in[5];
    float* dout = (float*)d_out;

    float* ws = (float*)d_ws;
    float* h0     = ws;                        // N*128
    float* ar     = h0 + NNODES * 128;         // N*2
    float* ac     = ar + NNODES * 2;           // N*2
    float* out0   = ac + NNODES * 2;           // N*64
    float* h1     = out0 + NNODES * 64;        // N*2
    int*   deg    = (int*)(h1 + NNODES * 2);   // N
    int*   rowptr = deg + NNODES;              // N+1
    int*   cur    = rowptr + NNODES + 1;       // N
    int*   ecol   = cur + NNODES;              // E

    // CSR build
    k_zero<<<(NNODES + 255) / 256, 256, 0, stream>>>(deg);
    k_hist<<<(NEDGES + 255) / 256, 256, 0, stream>>>(ei, deg);
    k_scan<<<1, 1024, 0, stream>>>(deg, rowptr, cur);
    k_scatter<<<(NEDGES + 255) / 256, 256, 0, stream>>>(ei, cur, ecol);

    // layer 0
    k_gemm0<<<(NNODES + 15) / 16, 256, 0, stream>>>(x, W0, h0);
    k_attn0<<<(NNODES * 64 + 255) / 256, 256, 0, stream>>>(h0, attn0, ar, ac);
    k_fused0<<<(NNODES * 64 + 255) / 256, 256, 0, stream>>>(rowptr, ecol, ar, ac, h0, out0);

    // layer 1
    k_node1<<<(NNODES * 64 + 255) / 256, 256, 0, stream>>>(out0, W1, h1);
    k_fused1<<<(NNODES + 255) / 256, 256, 0, stream>>>(rowptr, ecol, h1, attn1, dout);
}

// Round 3
// 276.114 us; speedup vs baseline: 1.6679x; 1.4140x over previous
//
#include <hip/hip_runtime.h>
#include <math.h>

#define NNODES 50000
#define NEDGES 800000
#define SCAN_NB ((NNODES + 255) / 256)   // 196

__device__ inline float wred64(float v) {
    #pragma unroll
    for (int off = 32; off; off >>= 1) v += __shfl_down(v, off, 64);
    return v;
}

// ---- zero the degree counters ----
__global__ void k_zero(int* __restrict__ deg) {
    int i = blockIdx.x * blockDim.x + threadIdx.x;
    if (i < NNODES) deg[i] = 0;
}

// ---- CSR build: histogram ----
__global__ __launch_bounds__(256) void k_hist(const int* __restrict__ ei, int* __restrict__ deg) {
    int e = blockIdx.x * blockDim.x + threadIdx.x;
    if (e >= NEDGES) return;
    atomicAdd(&deg[ei[e]], 1);
}

// ---- scan pass 1: per-block exclusive scan + block totals ----
__global__ __launch_bounds__(256) void k_scan1(const int* __restrict__ deg,
                                               int* __restrict__ rowptr,
                                               int* __restrict__ bsum) {
    __shared__ int sh[256];
    int t = threadIdx.x;
    int idx = blockIdx.x * 256 + t;
    int v = (idx < NNODES) ? deg[idx] : 0;
    sh[t] = v;
    __syncthreads();
    #pragma unroll
    for (int off = 1; off < 256; off <<= 1) {
        int u = (t >= off) ? sh[t - off] : 0;
        __syncthreads();
        sh[t] += u;
        __syncthreads();
    }
    if (idx < NNODES) rowptr[idx] = sh[t] - v;    // exclusive within block
    if (t == 255) bsum[blockIdx.x] = sh[255];
}

// ---- scan pass 2: scan the 196 block sums (one block) ----
__global__ __launch_bounds__(256) void k_scan2(const int* __restrict__ bsum,
                                               int* __restrict__ boff) {
    __shared__ int sh[256];
    int t = threadIdx.x;
    int v = (t < SCAN_NB) ? bsum[t] : 0;
    sh[t] = v;
    __syncthreads();
    #pragma unroll
    for (int off = 1; off < 256; off <<= 1) {
        int u = (t >= off) ? sh[t - off] : 0;
        __syncthreads();
        sh[t] += u;
        __syncthreads();
    }
    if (t < SCAN_NB) boff[t] = sh[t] - v;
}

// ---- scan pass 3: add block offsets; init cur; set sentinel ----
__global__ __launch_bounds__(256) void k_scan3(int* __restrict__ rowptr,
                                               const int* __restrict__ boff,
                                               int* __restrict__ cur) {
    int idx = blockIdx.x * 256 + threadIdx.x;
    if (idx < NNODES) {
        int r = rowptr[idx] + boff[blockIdx.x];
        rowptr[idx] = r;
        cur[idx] = r;
    }
    if (idx == 0) rowptr[NNODES] = NEDGES;
}

// ---- CSR build: scatter cols grouped by target row ----
__global__ __launch_bounds__(256) void k_scatter(const int* __restrict__ ei,
                                                 int* __restrict__ cur,
                                                 int* __restrict__ ecol) {
    int e = blockIdx.x * blockDim.x + threadIdx.x;
    if (e >= NEDGES) return;
    int row = ei[e], col = ei[NEDGES + e];
    int p = atomicAdd(&cur[row], 1);
    ecol[p] = col;
}

// ---- h0 = x @ W0  (N x 128)(128 x 128); 16 rows per 256-thread block ----
__global__ __launch_bounds__(256) void k_gemm0(const float* __restrict__ x,
                                               const float* __restrict__ W,
                                               float* __restrict__ h0) {
    __shared__ float xs[16 * 128];
    int n0 = blockIdx.x * 16;
    int t = threadIdx.x;
    for (int i = t; i < 16 * 128; i += 256) {
        int r = i >> 7, c = i & 127;
        int n = n0 + r;
        xs[i] = (n < NNODES) ? x[n * 128 + c] : 0.f;
    }
    __syncthreads();
    int j = t & 127;
    int rr = t >> 7;
    float acc[8];
    #pragma unroll
    for (int i = 0; i < 8; i++) acc[i] = 0.f;
    for (int k = 0; k < 128; k++) {
        float w = W[k * 128 + j];
        #pragma unroll
        for (int i = 0; i < 8; i++) acc[i] += xs[(rr + 2 * i) * 128 + k] * w;
    }
    #pragma unroll
    for (int i = 0; i < 8; i++) {
        int n = n0 + rr + 2 * i;
        if (n < NNODES) h0[n * 128 + j] = acc[i];
    }
}

// ---- per-node attention dots for layer 0: ar[n,h], ac[n,h] ----
__global__ __launch_bounds__(256) void k_attn0(const float* __restrict__ h0,
                                               const float* __restrict__ attn0,
                                               float* __restrict__ ar,
                                               float* __restrict__ ac) {
    int gt = blockIdx.x * blockDim.x + threadIdx.x;
    int n = gt >> 6, lane = gt & 63;
    if (n >= NNODES) return;
    float v0 = h0[n * 128 + lane];
    float v1 = h0[n * 128 + 64 + lane];
    float r0 = v0 * attn0[lane];
    float c0 = v0 * attn0[64 + lane];
    float r1 = v1 * attn0[128 + lane];
    float c1 = v1 * attn0[192 + lane];
    r0 = wred64(r0); c0 = wred64(c0); r1 = wred64(r1); c1 = wred64(c1);
    if (lane == 0) {
        ar[n * 2] = r0; ac[n * 2] = c0;
        ar[n * 2 + 1] = r1; ac[n * 2 + 1] = c1;
    }
}

// ---- layer 0 fully fused: per-node online softmax + aggregation + head mean ----
// one wave per node; lane = channel (0..63)
__global__ __launch_bounds__(256) void k_fused0(const int* __restrict__ rowptr,
                                                const int* __restrict__ ecol,
                                                const float* __restrict__ ar,
                                                const float* __restrict__ ac,
                                                const float* __restrict__ h0,
                                                float* __restrict__ out0) {
    int gt = blockIdx.x * blockDim.x + threadIdx.x;
    int n = gt >> 6, c = gt & 63;
    if (n >= NNODES) return;
    int beg = rowptr[n], end = rowptr[n + 1];
    float arn0 = ar[n * 2], arn1 = ar[n * 2 + 1];
    float m0 = -INFINITY, s0 = 0.f, acc0 = 0.f;
    float m1 = -INFINITY, s1 = 0.f, acc1 = 0.f;
    for (int i = beg; i < end; i++) {
        int col = ecol[i];
        float2 acv = *(const float2*)&ac[col * 2];
        float v0 = h0[col * 128 + c];
        float v1 = h0[col * 128 + 64 + c];
        float a0 = arn0 + acv.x;
        float a1 = arn1 + acv.y;
        a0 = a0 > 0.f ? a0 : 0.2f * a0;
        a1 = a1 > 0.f ? a1 : 0.2f * a1;
        float nm0 = fmaxf(m0, a0);
        float r0 = __expf(m0 - nm0);
        float p0 = __expf(a0 - nm0);
        s0 = s0 * r0 + p0;
        acc0 = acc0 * r0 + p0 * v0;
        m0 = nm0;
        float nm1 = fmaxf(m1, a1);
        float r1 = __expf(m1 - nm1);
        float p1 = __expf(a1 - nm1);
        s1 = s1 * r1 + p1;
        acc1 = acc1 * r1 + p1 * v1;
        m1 = nm1;
    }
    float o = (end > beg) ? 0.5f * (acc0 / s0 + acc1 / s1) : 0.f;
    out0[n * 64 + c] = o;
}

// ---- layer 1 node transform: h1 = relu(out0) @ W1  -> [N,2] ----
__global__ __launch_bounds__(256) void k_node1(const float* __restrict__ out0,
                                               const float* __restrict__ W1,
                                               float* __restrict__ h1) {
    int gt = blockIdx.x * blockDim.x + threadIdx.x;
    int n = gt >> 6, lane = gt & 63;
    if (n >= NNODES) return;
    float r = out0[n * 64 + lane];
    r = r > 0.f ? r : 0.f;
    float a = r * W1[lane * 2];
    float b = r * W1[lane * 2 + 1];
    a = wred64(a); b = wred64(b);
    if (lane == 0) { h1[n * 2] = a; h1[n * 2 + 1] = b; }
}

// ---- layer 1 fully fused: one THREAD per node ----
__global__ __launch_bounds__(256) void k_fused1(const int* __restrict__ rowptr,
                                                const int* __restrict__ ecol,
                                                const float* __restrict__ h1,
                                                const float* __restrict__ attn1,
                                                float* __restrict__ dout) {
    int n = blockIdx.x * blockDim.x + threadIdx.x;
    if (n >= NNODES) return;
    int beg = rowptr[n], end = rowptr[n + 1];
    float w00 = attn1[0], w01 = attn1[1];
    float w10 = attn1[2], w11 = attn1[3];
    float base0 = w00 * h1[n * 2];
    float base1 = w10 * h1[n * 2 + 1];
    float m0 = -INFINITY, s0 = 0.f, acc0 = 0.f;
    float m1 = -INFINITY, s1 = 0.f, acc1 = 0.f;
    for (int i = beg; i < end; i++) {
        int col = ecol[i];
        float2 v = *(const float2*)&h1[col * 2];
        float a0 = base0 + w01 * v.x;
        float a1 = base1 + w11 * v.y;
        a0 = a0 > 0.f ? a0 : 0.2f * a0;
        a1 = a1 > 0.f ? a1 : 0.2f * a1;
        float nm0 = fmaxf(m0, a0);
        float r0 = __expf(m0 - nm0);
        float p0 = __expf(a0 - nm0);
        s0 = s0 * r0 + p0;
        acc0 = acc0 * r0 + p0 * v.x;
        m0 = nm0;
        float nm1 = fmaxf(m1, a1);
        float r1 = __expf(m1 - nm1);
        float p1 = __expf(a1 - nm1);
        s1 = s1 * r1 + p1;
        acc1 = acc1 * r1 + p1 * v.y;
        m1 = nm1;
    }
    dout[n] = (end > beg) ? 0.5f * (acc0 / s0 + acc1 / s1) : 0.f;
}

extern "C" void kernel_launch(void* const* d_in, const int* in_sizes, int n_in,
                              void* d_out, int out_size, void* d_ws, size_t ws_size,
                              hipStream_t stream) {
    const float* x     = (const float*)d_in[0];
    const int*   ei    = (const int*)d_in[1];     // [2,E] int32 (row, col)
    const float* W0    = (const float*)d_in[2];
    const float* attn0 = (const float*)d_in[3];
    const float* W1    = (const float*)d_in[4];
    const float* attn1 = (const float*)d_in[5];
    float* dout = (float*)d_out;

    float* ws = (float*)d_ws;
    float* h0     = ws;                        // N*128
    float* ar     = h0 + NNODES * 128;         // N*2
    float* ac     = ar + NNODES * 2;           // N*2
    float* out0   = ac + NNODES * 2;           // N*64
    float* h1     = out0 + NNODES * 64;        // N*2
    int*   deg    = (int*)(h1 + NNODES * 2);   // N
    int*   rowptr = deg + NNODES;              // N+1
    int*   cur    = rowptr + NNODES + 1;       // N
    int*   bsum   = cur + NNODES;              // SCAN_NB
    int*   boff   = bsum + SCAN_NB;            // SCAN_NB
    int*   ecol   = boff + SCAN_NB;            // E

    // CSR build
    k_zero<<<(NNODES + 255) / 256, 256, 0, stream>>>(deg);
    k_hist<<<(NEDGES + 255) / 256, 256, 0, stream>>>(ei, deg);
    k_scan1<<<SCAN_NB, 256, 0, stream>>>(deg, rowptr, bsum);
    k_scan2<<<1, 256, 0, stream>>>(bsum, boff);
    k_scan3<<<SCAN_NB, 256, 0, stream>>>(rowptr, boff, cur);
    k_scatter<<<(NEDGES + 255) / 256, 256, 0, stream>>>(ei, cur, ecol);

    // layer 0
    k_gemm0<<<(NNODES + 15) / 16, 256, 0, stream>>>(x, W0, h0);
    k_attn0<<<(NNODES * 64 + 255) / 256, 256, 0, stream>>>(h0, attn0, ar, ac);
    k_fused0<<<(NNODES * 64 + 255) / 256, 256, 0, stream>>>(rowptr, ecol, ar, ac, h0, out0);

    // layer 1
    k_node1<<<(NNODES * 64 + 255) / 256, 256, 0, stream>>>(out0, W1, h1);
    k_fused1<<<(NNODES + 255) / 256, 256, 0, stream>>>(rowptr, ecol, h1, attn1, dout);
}

// Round 4
// 253.000 us; speedup vs baseline: 1.8203x; 1.0914x over previous
//
#include <hip/hip_runtime.h>
#include <math.h>

#define NNODES 50000
#define NEDGES 800000
#define SCAN_NB ((NNODES + 255) / 256)   // 196

// butterfly reductions: result valid in ALL lanes
__device__ inline float bsum64(float v) {
    #pragma unroll
    for (int off = 1; off < 64; off <<= 1) v += __shfl_xor(v, off, 64);
    return v;
}
__device__ inline float bmax64(float v) {
    #pragma unroll
    for (int off = 1; off < 64; off <<= 1) v = fmaxf(v, __shfl_xor(v, off, 64));
    return v;
}

// ---- zero the degree counters ----
__global__ void k_zero(int* __restrict__ deg) {
    int i = blockIdx.x * blockDim.x + threadIdx.x;
    if (i < NNODES) deg[i] = 0;
}

// ---- CSR build: histogram ----
__global__ __launch_bounds__(256) void k_hist(const int* __restrict__ ei, int* __restrict__ deg) {
    int e = blockIdx.x * blockDim.x + threadIdx.x;
    if (e >= NEDGES) return;
    atomicAdd(&deg[ei[e]], 1);
}

// ---- scan pass 1: per-block exclusive scan + block totals ----
__global__ __launch_bounds__(256) void k_scan1(const int* __restrict__ deg,
                                               int* __restrict__ rowptr,
                                               int* __restrict__ bsum) {
    __shared__ int sh[256];
    int t = threadIdx.x;
    int idx = blockIdx.x * 256 + t;
    int v = (idx < NNODES) ? deg[idx] : 0;
    sh[t] = v;
    __syncthreads();
    #pragma unroll
    for (int off = 1; off < 256; off <<= 1) {
        int u = (t >= off) ? sh[t - off] : 0;
        __syncthreads();
        sh[t] += u;
        __syncthreads();
    }
    if (idx < NNODES) rowptr[idx] = sh[t] - v;
    if (t == 255) bsum[blockIdx.x] = sh[255];
}

// ---- scan pass 2: scan the 196 block sums ----
__global__ __launch_bounds__(256) void k_scan2(const int* __restrict__ bsum,
                                               int* __restrict__ boff) {
    __shared__ int sh[256];
    int t = threadIdx.x;
    int v = (t < SCAN_NB) ? bsum[t] : 0;
    sh[t] = v;
    __syncthreads();
    #pragma unroll
    for (int off = 1; off < 256; off <<= 1) {
        int u = (t >= off) ? sh[t - off] : 0;
        __syncthreads();
        sh[t] += u;
        __syncthreads();
    }
    if (t < SCAN_NB) boff[t] = sh[t] - v;
}

// ---- scan pass 3: add block offsets; init cur; sentinel ----
__global__ __launch_bounds__(256) void k_scan3(int* __restrict__ rowptr,
                                               const int* __restrict__ boff,
                                               int* __restrict__ cur) {
    int idx = blockIdx.x * 256 + threadIdx.x;
    if (idx < NNODES) {
        int r = rowptr[idx] + boff[blockIdx.x];
        rowptr[idx] = r;
        cur[idx] = r;
    }
    if (idx == 0) rowptr[NNODES] = NEDGES;
}

// ---- CSR build: scatter cols grouped by target row ----
__global__ __launch_bounds__(256) void k_scatter(const int* __restrict__ ei,
                                                 int* __restrict__ cur,
                                                 int* __restrict__ ecol) {
    int e = blockIdx.x * blockDim.x + threadIdx.x;
    if (e >= NEDGES) return;
    int row = ei[e], col = ei[NEDGES + e];
    int p = atomicAdd(&cur[row], 1);
    ecol[p] = col;
}

// ---- h0 = x @ W0 ----
__global__ __launch_bounds__(256) void k_gemm0(const float* __restrict__ x,
                                               const float* __restrict__ W,
                                               float* __restrict__ h0) {
    __shared__ float xs[16 * 128];
    int n0 = blockIdx.x * 16;
    int t = threadIdx.x;
    for (int i = t; i < 16 * 128; i += 256) {
        int r = i >> 7, c = i & 127;
        int n = n0 + r;
        xs[i] = (n < NNODES) ? x[n * 128 + c] : 0.f;
    }
    __syncthreads();
    int j = t & 127;
    int rr = t >> 7;
    float acc[8];
    #pragma unroll
    for (int i = 0; i < 8; i++) acc[i] = 0.f;
    for (int k = 0; k < 128; k++) {
        float w = W[k * 128 + j];
        #pragma unroll
        for (int i = 0; i < 8; i++) acc[i] += xs[(rr + 2 * i) * 128 + k] * w;
    }
    #pragma unroll
    for (int i = 0; i < 8; i++) {
        int n = n0 + rr + 2 * i;
        if (n < NNODES) h0[n * 128 + j] = acc[i];
    }
}

// ---- per-node attention dots: ar[n,h], ac[n,h] ----
__global__ __launch_bounds__(256) void k_attn0(const float* __restrict__ h0,
                                               const float* __restrict__ attn0,
                                               float* __restrict__ ar,
                                               float* __restrict__ ac) {
    int gt = blockIdx.x * blockDim.x + threadIdx.x;
    int n = gt >> 6, lane = gt & 63;
    if (n >= NNODES) return;
    float v0 = h0[n * 128 + lane];
    float v1 = h0[n * 128 + 64 + lane];
    float r0 = bsum64(v0 * attn0[lane]);
    float c0 = bsum64(v0 * attn0[64 + lane]);
    float r1 = bsum64(v1 * attn0[128 + lane]);
    float c1 = bsum64(v1 * attn0[192 + lane]);
    if (lane == 0) {
        ar[n * 2] = r0; ac[n * 2] = c0;
        ar[n * 2 + 1] = r1; ac[n * 2 + 1] = c1;
    }
}

// ---- layer 0 softmax weights: one wave per node, lane = edge ----
// writes ewt[e] = {p0,p1} (unnormalized exp) and sc[n] = {0.5/s0, 0.5/s1}
__global__ __launch_bounds__(256) void k_wt0(const int* __restrict__ rowptr,
                                             const int* __restrict__ ecol,
                                             const float* __restrict__ ar,
                                             const float* __restrict__ ac,
                                             float2* __restrict__ ewt,
                                             float2* __restrict__ sc) {
    int n = blockIdx.x * 4 + (threadIdx.x >> 6);
    int lane = threadIdx.x & 63;
    if (n >= NNODES) return;
    int beg = rowptr[n], end = rowptr[n + 1];
    if (beg == end) {
        if (lane == 0) sc[n] = make_float2(0.f, 0.f);
        return;
    }
    float arn0 = ar[n * 2], arn1 = ar[n * 2 + 1];
    // pass 1: max
    float mm0 = -INFINITY, mm1 = -INFINITY;
    for (int base = beg; base < end; base += 64) {
        int i = base + lane;
        if (i < end) {
            float2 acv = *(const float2*)&ac[ecol[i] * 2];
            float a0 = arn0 + acv.x, a1 = arn1 + acv.y;
            a0 = a0 > 0.f ? a0 : 0.2f * a0;
            a1 = a1 > 0.f ? a1 : 0.2f * a1;
            mm0 = fmaxf(mm0, a0); mm1 = fmaxf(mm1, a1);
        }
    }
    float m0 = bmax64(mm0), m1 = bmax64(mm1);
    // pass 2: exp, store, sum
    float ss0 = 0.f, ss1 = 0.f;
    for (int base = beg; base < end; base += 64) {
        int i = base + lane;
        if (i < end) {
            float2 acv = *(const float2*)&ac[ecol[i] * 2];
            float a0 = arn0 + acv.x, a1 = arn1 + acv.y;
            a0 = a0 > 0.f ? a0 : 0.2f * a0;
            a1 = a1 > 0.f ? a1 : 0.2f * a1;
            float p0 = __expf(a0 - m0), p1 = __expf(a1 - m1);
            ewt[i] = make_float2(p0, p1);
            ss0 += p0; ss1 += p1;
        }
    }
    float s0 = bsum64(ss0), s1 = bsum64(ss1);
    if (lane == 0) sc[n] = make_float2(0.5f / s0, 0.5f / s1);
}

// ---- layer 0 aggregation + fused relu + W1 transform -> h1[N,2] ----
// one wave per node; lane = channel
__global__ __launch_bounds__(256) void k_agg0(const int* __restrict__ rowptr,
                                              const int* __restrict__ ecol,
                                              const float2* __restrict__ ewt,
                                              const float2* __restrict__ sc,
                                              const float* __restrict__ h0,
                                              const float* __restrict__ W1,
                                              float* __restrict__ h1) {
    int n = blockIdx.x * 4 + (threadIdx.x >> 6);
    int c = threadIdx.x & 63;
    if (n >= NNODES) return;
    int beg = rowptr[n], end = rowptr[n + 1];
    float2 si = sc[n];
    float acc0 = 0.f, acc1 = 0.f, acc0b = 0.f, acc1b = 0.f;
    int i = beg;
    for (; i + 1 < end; i += 2) {
        int colA = ecol[i], colB = ecol[i + 1];
        float2 wA = ewt[i], wB = ewt[i + 1];
        acc0  += wA.x * h0[colA * 128 + c];
        acc1  += wA.y * h0[colA * 128 + 64 + c];
        acc0b += wB.x * h0[colB * 128 + c];
        acc1b += wB.y * h0[colB * 128 + 64 + c];
    }
    if (i < end) {
        int col = ecol[i];
        float2 w = ewt[i];
        acc0 += w.x * h0[col * 128 + c];
        acc1 += w.y * h0[col * 128 + 64 + c];
    }
    float o = si.x * (acc0 + acc0b) + si.y * (acc1 + acc1b);
    o = o > 0.f ? o : 0.f;   // relu
    float A = bsum64(o * W1[c * 2]);
    float B = bsum64(o * W1[c * 2 + 1]);
    if (c == 0) { h1[n * 2] = A; h1[n * 2 + 1] = B; }
}

// ---- layer 1 fully fused: wave per node, lane = edge, chunk-online softmax ----
__global__ __launch_bounds__(256) void k_fused1(const int* __restrict__ rowptr,
                                                const int* __restrict__ ecol,
                                                const float* __restrict__ h1,
                                                const float* __restrict__ attn1,
                                                float* __restrict__ dout) {
    int n = blockIdx.x * 4 + (threadIdx.x >> 6);
    int lane = threadIdx.x & 63;
    if (n >= NNODES) return;
    int beg = rowptr[n], end = rowptr[n + 1];
    if (beg == end) { if (lane == 0) dout[n] = 0.f; return; }
    float w00 = attn1[0], w01 = attn1[1];
    float w10 = attn1[2], w11 = attn1[3];
    float base0 = w00 * h1[n * 2];
    float base1 = w10 * h1[n * 2 + 1];
    float m0 = -INFINITY, s0 = 0.f, acc0 = 0.f;
    float m1 = -INFINITY, s1 = 0.f, acc1 = 0.f;
    for (int base = beg; base < end; base += 64) {
        int i = base + lane;
        bool act = i < end;
        int col = act ? ecol[i] : 0;
        float2 v = *(const float2*)&h1[col * 2];
        float a0 = act ? (base0 + w01 * v.x) : -INFINITY;
        float a1 = act ? (base1 + w11 * v.y) : -INFINITY;
        a0 = a0 > 0.f ? a0 : 0.2f * a0;
        a1 = a1 > 0.f ? a1 : 0.2f * a1;
        float cm0 = bmax64(a0), cm1 = bmax64(a1);
        float nm0 = fmaxf(m0, cm0), nm1 = fmaxf(m1, cm1);
        float r0 = __expf(m0 - nm0), r1 = __expf(m1 - nm1);
        float p0 = __expf(a0 - nm0), p1 = __expf(a1 - nm1);
        s0 = s0 * r0 + bsum64(p0);
        acc0 = acc0 * r0 + bsum64(p0 * v.x);
        s1 = s1 * r1 + bsum64(p1);
        acc1 = acc1 * r1 + bsum64(p1 * v.y);
        m0 = nm0; m1 = nm1;
    }
    if (lane == 0) dout[n] = 0.5f * (acc0 / s0 + acc1 / s1);
}

extern "C" void kernel_launch(void* const* d_in, const int* in_sizes, int n_in,
                              void* d_out, int out_size, void* d_ws, size_t ws_size,
                              hipStream_t stream) {
    const float* x     = (const float*)d_in[0];
    const int*   ei    = (const int*)d_in[1];
    const float* W0    = (const float*)d_in[2];
    const float* attn0 = (const float*)d_in[3];
    const float* W1    = (const float*)d_in[4];
    const float* attn1 = (const float*)d_in[5];
    float* dout = (float*)d_out;

    float* ws = (float*)d_ws;
    float*  h0     = ws;                         // N*128
    float*  ar     = h0 + NNODES * 128;          // N*2
    float*  ac     = ar + NNODES * 2;            // N*2
    float2* ewt    = (float2*)(ac + NNODES * 2); // E (float2)
    float2* sc     = ewt + NEDGES;               // N (float2)
    float*  h1     = (float*)(sc + NNODES);      // N*2
    int*    deg    = (int*)(h1 + NNODES * 2);    // N
    int*    rowptr = deg + NNODES;               // N+1
    int*    cur    = rowptr + NNODES + 1;        // N
    int*    bsum   = cur + NNODES;               // SCAN_NB
    int*    boff   = bsum + SCAN_NB;             // SCAN_NB
    int*    ecol   = boff + SCAN_NB;             // E

    // CSR build
    k_zero<<<(NNODES + 255) / 256, 256, 0, stream>>>(deg);
    k_hist<<<(NEDGES + 255) / 256, 256, 0, stream>>>(ei, deg);
    k_scan1<<<SCAN_NB, 256, 0, stream>>>(deg, rowptr, bsum);
    k_scan2<<<1, 256, 0, stream>>>(bsum, boff);
    k_scan3<<<SCAN_NB, 256, 0, stream>>>(rowptr, boff, cur);
    k_scatter<<<(NEDGES + 255) / 256, 256, 0, stream>>>(ei, cur, ecol);

    // layer 0
    k_gemm0<<<(NNODES + 15) / 16, 256, 0, stream>>>(x, W0, h0);
    k_attn0<<<(NNODES * 64 + 255) / 256, 256, 0, stream>>>(h0, attn0, ar, ac);
    k_wt0<<<(NNODES + 3) / 4, 256, 0, stream>>>(rowptr, ecol, ar, ac, ewt, sc);
    k_agg0<<<(NNODES + 3) / 4, 256, 0, stream>>>(rowptr, ecol, ewt, sc, h0, W1, h1);

    // layer 1
    k_fused1<<<(NNODES + 3) / 4, 256, 0, stream>>>(rowptr, ecol, h1, attn1, dout);
}

// Round 5
// 211.991 us; speedup vs baseline: 2.1724x; 1.1934x over previous
//
#include <hip/hip_runtime.h>
#include <math.h>

#define NNODES 50000
#define NEDGES 800000
#define SCAN_NB ((NNODES + 255) / 256)   // 196

// butterfly reductions: result valid in ALL lanes
__device__ inline float bsum64(float v) {
    #pragma unroll
    for (int off = 1; off < 64; off <<= 1) v += __shfl_xor(v, off, 64);
    return v;
}
__device__ inline float bmax64(float v) {
    #pragma unroll
    for (int off = 1; off < 64; off <<= 1) v = fmaxf(v, __shfl_xor(v, off, 64));
    return v;
}

// pack two f32 -> 2x bf16 (RNE) in one uint
__device__ inline unsigned packbf2(float a, float b) {
    unsigned ua = __float_as_uint(a);
    unsigned ub = __float_as_uint(b);
    ua = (ua + 0x7fffu + ((ua >> 16) & 1u)) >> 16;
    ub = (ub + 0x7fffu + ((ub >> 16) & 1u)) >> 16;
    return ua | (ub << 16);
}

// ---- zero the degree counters ----
__global__ void k_zero(int* __restrict__ deg) {
    int i = blockIdx.x * blockDim.x + threadIdx.x;
    if (i < NNODES) deg[i] = 0;
}

// ---- CSR build: histogram + per-edge local rank (coalesced write) ----
__global__ __launch_bounds__(256) void k_hist(const int* __restrict__ ei,
                                              int* __restrict__ deg,
                                              int* __restrict__ erank) {
    int e = blockIdx.x * blockDim.x + threadIdx.x;
    if (e >= NEDGES) return;
    erank[e] = atomicAdd(&deg[ei[e]], 1);
}

// ---- scan pass 1: per-block exclusive scan + block totals ----
__global__ __launch_bounds__(256) void k_scan1(const int* __restrict__ deg,
                                               int* __restrict__ rowptr,
                                               int* __restrict__ bsum) {
    __shared__ int sh[256];
    int t = threadIdx.x;
    int idx = blockIdx.x * 256 + t;
    int v = (idx < NNODES) ? deg[idx] : 0;
    sh[t] = v;
    __syncthreads();
    #pragma unroll
    for (int off = 1; off < 256; off <<= 1) {
        int u = (t >= off) ? sh[t - off] : 0;
        __syncthreads();
        sh[t] += u;
        __syncthreads();
    }
    if (idx < NNODES) rowptr[idx] = sh[t] - v;
    if (t == 255) bsum[blockIdx.x] = sh[255];
}

// ---- scan pass 2: scan the 196 block sums ----
__global__ __launch_bounds__(256) void k_scan2(const int* __restrict__ bsum,
                                               int* __restrict__ boff) {
    __shared__ int sh[256];
    int t = threadIdx.x;
    int v = (t < SCAN_NB) ? bsum[t] : 0;
    sh[t] = v;
    __syncthreads();
    #pragma unroll
    for (int off = 1; off < 256; off <<= 1) {
        int u = (t >= off) ? sh[t - off] : 0;
        __syncthreads();
        sh[t] += u;
        __syncthreads();
    }
    if (t < SCAN_NB) boff[t] = sh[t] - v;
}

// ---- scan pass 3: add block offsets; sentinel ----
__global__ __launch_bounds__(256) void k_scan3(int* __restrict__ rowptr,
                                               const int* __restrict__ boff) {
    int idx = blockIdx.x * 256 + threadIdx.x;
    if (idx < NNODES) rowptr[idx] += boff[blockIdx.x];
    if (idx == 0) rowptr[NNODES] = NEDGES;
}

// ---- CSR build: scatter cols (no atomic; rank precomputed) ----
__global__ __launch_bounds__(256) void k_scatter(const int* __restrict__ ei,
                                                 const int* __restrict__ rowptr,
                                                 const int* __restrict__ erank,
                                                 int* __restrict__ ecol) {
    int e = blockIdx.x * blockDim.x + threadIdx.x;
    if (e >= NEDGES) return;
    int row = ei[e], col = ei[NEDGES + e];
    ecol[rowptr[row] + erank[e]] = col;
}

// ---- h0 = x @ W0 ----
__global__ __launch_bounds__(256) void k_gemm0(const float* __restrict__ x,
                                               const float* __restrict__ W,
                                               float* __restrict__ h0) {
    __shared__ float xs[16 * 128];
    int n0 = blockIdx.x * 16;
    int t = threadIdx.x;
    for (int i = t; i < 16 * 128; i += 256) {
        int r = i >> 7, c = i & 127;
        int n = n0 + r;
        xs[i] = (n < NNODES) ? x[n * 128 + c] : 0.f;
    }
    __syncthreads();
    int j = t & 127;
    int rr = t >> 7;
    float acc[8];
    #pragma unroll
    for (int i = 0; i < 8; i++) acc[i] = 0.f;
    for (int k = 0; k < 128; k++) {
        float w = W[k * 128 + j];
        #pragma unroll
        for (int i = 0; i < 8; i++) acc[i] += xs[(rr + 2 * i) * 128 + k] * w;
    }
    #pragma unroll
    for (int i = 0; i < 8; i++) {
        int n = n0 + rr + 2 * i;
        if (n < NNODES) h0[n * 128 + j] = acc[i];
    }
}

// ---- per-node attention dots + bf16 pack of h0 values ----
__global__ __launch_bounds__(256) void k_attn0(const float* __restrict__ h0,
                                               const float* __restrict__ attn0,
                                               float* __restrict__ ar,
                                               float* __restrict__ ac,
                                               unsigned* __restrict__ h0b) {
    int gt = blockIdx.x * blockDim.x + threadIdx.x;
    int n = gt >> 6, lane = gt & 63;
    if (n >= NNODES) return;
    float v0 = h0[n * 128 + lane];
    float v1 = h0[n * 128 + 64 + lane];
    h0b[n * 64 + lane] = packbf2(v0, v1);   // both heads, one 4B word
    float r0 = bsum64(v0 * attn0[lane]);
    float c0 = bsum64(v0 * attn0[64 + lane]);
    float r1 = bsum64(v1 * attn0[128 + lane]);
    float c1 = bsum64(v1 * attn0[192 + lane]);
    if (lane == 0) {
        ar[n * 2] = r0; ac[n * 2] = c0;
        ar[n * 2 + 1] = r1; ac[n * 2 + 1] = c1;
    }
}

// ---- layer 0 softmax weights: one wave per node, lane = edge ----
__global__ __launch_bounds__(256) void k_wt0(const int* __restrict__ rowptr,
                                             const int* __restrict__ ecol,
                                             const float* __restrict__ ar,
                                             const float* __restrict__ ac,
                                             float2* __restrict__ ewt,
                                             float2* __restrict__ sc) {
    int n = blockIdx.x * 4 + (threadIdx.x >> 6);
    int lane = threadIdx.x & 63;
    if (n >= NNODES) return;
    int beg = rowptr[n], end = rowptr[n + 1];
    if (beg == end) {
        if (lane == 0) sc[n] = make_float2(0.f, 0.f);
        return;
    }
    float arn0 = ar[n * 2], arn1 = ar[n * 2 + 1];
    float mm0 = -INFINITY, mm1 = -INFINITY;
    for (int base = beg; base < end; base += 64) {
        int i = base + lane;
        if (i < end) {
            float2 acv = *(const float2*)&ac[ecol[i] * 2];
            float a0 = arn0 + acv.x, a1 = arn1 + acv.y;
            a0 = a0 > 0.f ? a0 : 0.2f * a0;
            a1 = a1 > 0.f ? a1 : 0.2f * a1;
            mm0 = fmaxf(mm0, a0); mm1 = fmaxf(mm1, a1);
        }
    }
    float m0 = bmax64(mm0), m1 = bmax64(mm1);
    float ss0 = 0.f, ss1 = 0.f;
    for (int base = beg; base < end; base += 64) {
        int i = base + lane;
        if (i < end) {
            float2 acv = *(const float2*)&ac[ecol[i] * 2];
            float a0 = arn0 + acv.x, a1 = arn1 + acv.y;
            a0 = a0 > 0.f ? a0 : 0.2f * a0;
            a1 = a1 > 0.f ? a1 : 0.2f * a1;
            float p0 = __expf(a0 - m0), p1 = __expf(a1 - m1);
            ewt[i] = make_float2(p0, p1);
            ss0 += p0; ss1 += p1;
        }
    }
    float s0 = bsum64(ss0), s1 = bsum64(ss1);
    if (lane == 0) sc[n] = make_float2(0.5f / s0, 0.5f / s1);
}

// ---- layer 0 aggregation (bf16 packed gather) + relu + W1 -> h1[N,2] ----
__global__ __launch_bounds__(256) void k_agg0(const int* __restrict__ rowptr,
                                              const int* __restrict__ ecol,
                                              const float2* __restrict__ ewt,
                                              const float2* __restrict__ sc,
                                              const unsigned* __restrict__ h0b,
                                              const float* __restrict__ W1,
                                              float* __restrict__ h1) {
    int n = blockIdx.x * 4 + (threadIdx.x >> 6);
    int c = threadIdx.x & 63;
    if (n >= NNODES) return;
    int beg = rowptr[n], end = rowptr[n + 1];
    float2 si = sc[n];
    float acc0 = 0.f, acc1 = 0.f, acc0b = 0.f, acc1b = 0.f;
    int i = beg;
    for (; i + 1 < end; i += 2) {
        int colA = ecol[i], colB = ecol[i + 1];
        float2 wA = ewt[i], wB = ewt[i + 1];
        unsigned uA = h0b[colA * 64 + c];
        unsigned uB = h0b[colB * 64 + c];
        acc0  += wA.x * __uint_as_float(uA << 16);
        acc1  += wA.y * __uint_as_float(uA & 0xffff0000u);
        acc0b += wB.x * __uint_as_float(uB << 16);
        acc1b += wB.y * __uint_as_float(uB & 0xffff0000u);
    }
    if (i < end) {
        int col = ecol[i];
        float2 w = ewt[i];
        unsigned u = h0b[col * 64 + c];
        acc0 += w.x * __uint_as_float(u << 16);
        acc1 += w.y * __uint_as_float(u & 0xffff0000u);
    }
    float o = si.x * (acc0 + acc0b) + si.y * (acc1 + acc1b);
    o = o > 0.f ? o : 0.f;   // relu
    float A = bsum64(o * W1[c * 2]);
    float B = bsum64(o * W1[c * 2 + 1]);
    if (c == 0) { h1[n * 2] = A; h1[n * 2 + 1] = B; }
}

// ---- layer 1 fully fused: wave per node, lane = edge ----
__global__ __launch_bounds__(256) void k_fused1(const int* __restrict__ rowptr,
                                                const int* __restrict__ ecol,
                                                const float* __restrict__ h1,
                                                const float* __restrict__ attn1,
                                                float* __restrict__ dout) {
    int n = blockIdx.x * 4 + (threadIdx.x >> 6);
    int lane = threadIdx.x & 63;
    if (n >= NNODES) return;
    int beg = rowptr[n], end = rowptr[n + 1];
    if (beg == end) { if (lane == 0) dout[n] = 0.f; return; }
    float w00 = attn1[0], w01 = attn1[1];
    float w10 = attn1[2], w11 = attn1[3];
    float base0 = w00 * h1[n * 2];
    float base1 = w10 * h1[n * 2 + 1];
    float m0 = -INFINITY, s0 = 0.f, acc0 = 0.f;
    float m1 = -INFINITY, s1 = 0.f, acc1 = 0.f;
    for (int base = beg; base < end; base += 64) {
        int i = base + lane;
        bool act = i < end;
        int col = act ? ecol[i] : 0;
        float2 v = *(const float2*)&h1[col * 2];
        float a0 = act ? (base0 + w01 * v.x) : -INFINITY;
        float a1 = act ? (base1 + w11 * v.y) : -INFINITY;
        a0 = a0 > 0.f ? a0 : 0.2f * a0;
        a1 = a1 > 0.f ? a1 : 0.2f * a1;
        float cm0 = bmax64(a0), cm1 = bmax64(a1);
        float nm0 = fmaxf(m0, cm0), nm1 = fmaxf(m1, cm1);
        float r0 = __expf(m0 - nm0), r1 = __expf(m1 - nm1);
        float p0 = __expf(a0 - nm0), p1 = __expf(a1 - nm1);
        s0 = s0 * r0 + bsum64(p0);
        acc0 = acc0 * r0 + bsum64(p0 * v.x);
        s1 = s1 * r1 + bsum64(p1);
        acc1 = acc1 * r1 + bsum64(p1 * v.y);
        m0 = nm0; m1 = nm1;
    }
    if (lane == 0) dout[n] = 0.5f * (acc0 / s0 + acc1 / s1);
}

extern "C" void kernel_launch(void* const* d_in, const int* in_sizes, int n_in,
                              void* d_out, int out_size, void* d_ws, size_t ws_size,
                              hipStream_t stream) {
    const float* x     = (const float*)d_in[0];
    const int*   ei    = (const int*)d_in[1];
    const float* W0    = (const float*)d_in[2];
    const float* attn0 = (const float*)d_in[3];
    const float* W1    = (const float*)d_in[4];
    const float* attn1 = (const float*)d_in[5];
    float* dout = (float*)d_out;

    float* ws = (float*)d_ws;
    float*    h0     = ws;                          // N*128
    float*    ar     = h0 + NNODES * 128;           // N*2
    float*    ac     = ar + NNODES * 2;             // N*2
    float2*   ewt    = (float2*)(ac + NNODES * 2);  // E float2
    float2*   sc     = ewt + NEDGES;                // N float2
    float*    h1     = (float*)(sc + NNODES);       // N*2
    unsigned* h0b    = (unsigned*)(h1 + NNODES * 2);// N*64
    int*      deg    = (int*)(h0b + NNODES * 64);   // N
    int*      rowptr = deg + NNODES;                // N+1
    int*      erank  = rowptr + NNODES + 1;         // E
    int*      bsum   = erank + NEDGES;              // SCAN_NB
    int*      boff   = bsum + SCAN_NB;              // SCAN_NB
    int*      ecol   = boff + SCAN_NB;              // E

    // CSR build
    k_zero<<<(NNODES + 255) / 256, 256, 0, stream>>>(deg);
    k_hist<<<(NEDGES + 255) / 256, 256, 0, stream>>>(ei, deg, erank);
    k_scan1<<<SCAN_NB, 256, 0, stream>>>(deg, rowptr, bsum);
    k_scan2<<<1, 256, 0, stream>>>(bsum, boff);
    k_scan3<<<SCAN_NB, 256, 0, stream>>>(rowptr, boff);
    k_scatter<<<(NEDGES + 255) / 256, 256, 0, stream>>>(ei, rowptr, erank, ecol);

    // layer 0
    k_gemm0<<<(NNODES + 15) / 16, 256, 0, stream>>>(x, W0, h0);
    k_attn0<<<(NNODES * 64 + 255) / 256, 256, 0, stream>>>(h0, attn0, ar, ac, h0b);
    k_wt0<<<(NNODES + 3) / 4, 256, 0, stream>>>(rowptr, ecol, ar, ac, ewt, sc);
    k_agg0<<<(NNODES + 3) / 4, 256, 0, stream>>>(rowptr, ecol, ewt, sc, h0b, W1, h1);

    // layer 1
    k_fused1<<<(NNODES + 3) / 4, 256, 0, stream>>>(rowptr, ecol, h1, attn1, dout);
}

// Round 6
// 162.813 us; speedup vs baseline: 2.8286x; 1.3021x over previous
//
#include <hip/hip_runtime.h>
#include <math.h>

#define NNODES 50000
#define NEDGES 800000
#define SCAN_NB ((NNODES + 255) / 256)   // 196

// butterfly reductions: result valid in ALL lanes
__device__ inline float bsum64(float v) {
    #pragma unroll
    for (int off = 1; off < 64; off <<= 1) v += __shfl_xor(v, off, 64);
    return v;
}

// pack two f32 -> 2x bf16 (RNE) in one uint
__device__ inline unsigned packbf2(float a, float b) {
    unsigned ua = __float_as_uint(a);
    unsigned ub = __float_as_uint(b);
    ua = (ua + 0x7fffu + ((ua >> 16) & 1u)) >> 16;
    ub = (ub + 0x7fffu + ((ub >> 16) & 1u)) >> 16;
    return ua | (ub << 16);
}
__device__ inline float bflo(unsigned u) { return __uint_as_float(u << 16); }
__device__ inline float bfhi(unsigned u) { return __uint_as_float(u & 0xffff0000u); }

// ---- zero the degree counters ----
__global__ void k_zero(int* __restrict__ deg) {
    int i = blockIdx.x * blockDim.x + threadIdx.x;
    if (i < NNODES) deg[i] = 0;
}

// ---- CSR build: histogram + per-edge local rank ----
__global__ __launch_bounds__(256) void k_hist(const int* __restrict__ ei,
                                              int* __restrict__ deg,
                                              int* __restrict__ erank) {
    int e = blockIdx.x * blockDim.x + threadIdx.x;
    if (e >= NEDGES) return;
    erank[e] = atomicAdd(&deg[ei[e]], 1);
}

// ---- scan pass 1 ----
__global__ __launch_bounds__(256) void k_scan1(const int* __restrict__ deg,
                                               int* __restrict__ rowptr,
                                               int* __restrict__ bsum) {
    __shared__ int sh[256];
    int t = threadIdx.x;
    int idx = blockIdx.x * 256 + t;
    int v = (idx < NNODES) ? deg[idx] : 0;
    sh[t] = v;
    __syncthreads();
    #pragma unroll
    for (int off = 1; off < 256; off <<= 1) {
        int u = (t >= off) ? sh[t - off] : 0;
        __syncthreads();
        sh[t] += u;
        __syncthreads();
    }
    if (idx < NNODES) rowptr[idx] = sh[t] - v;
    if (t == 255) bsum[blockIdx.x] = sh[255];
}

// ---- scan pass 2 ----
__global__ __launch_bounds__(256) void k_scan2(const int* __restrict__ bsum,
                                               int* __restrict__ boff) {
    __shared__ int sh[256];
    int t = threadIdx.x;
    int v = (t < SCAN_NB) ? bsum[t] : 0;
    sh[t] = v;
    __syncthreads();
    #pragma unroll
    for (int off = 1; off < 256; off <<= 1) {
        int u = (t >= off) ? sh[t - off] : 0;
        __syncthreads();
        sh[t] += u;
        __syncthreads();
    }
    if (t < SCAN_NB) boff[t] = sh[t] - v;
}

// ---- scan pass 3 ----
__global__ __launch_bounds__(256) void k_scan3(int* __restrict__ rowptr,
                                               const int* __restrict__ boff) {
    int idx = blockIdx.x * 256 + threadIdx.x;
    if (idx < NNODES) rowptr[idx] += boff[blockIdx.x];
    if (idx == 0) rowptr[NNODES] = NEDGES;
}

// ---- CSR build: scatter (no atomic) ----
__global__ __launch_bounds__(256) void k_scatter(const int* __restrict__ ei,
                                                 const int* __restrict__ rowptr,
                                                 const int* __restrict__ erank,
                                                 int* __restrict__ ecol) {
    int e = blockIdx.x * blockDim.x + threadIdx.x;
    if (e >= NEDGES) return;
    int row = ei[e], col = ei[NEDGES + e];
    ecol[rowptr[row] + erank[e]] = col;
}

// ---- layer 0 node work: GEMM + attention dots + bf16 pack (h0 f32 never stored) ----
// 16 rows per 256-thread block; NNODES % 16 == 0
__global__ __launch_bounds__(256) void k_l0node(const float* __restrict__ x,
                                                const float* __restrict__ W,
                                                const float* __restrict__ attn0,
                                                float* __restrict__ ar,
                                                float* __restrict__ ac,
                                                unsigned* __restrict__ h0b) {
    __shared__ float xs[16 * 128];
    int n0 = blockIdx.x * 16;
    int t = threadIdx.x;
    for (int i = t; i < 16 * 128; i += 256) {
        int r = i >> 7, c = i & 127;
        xs[i] = x[(n0 + r) * 128 + c];
    }
    __syncthreads();
    int j = t & 127;     // output column 0..127
    int rr = t >> 7;     // 0..1 (even/odd row sets)
    float acc[8];
    #pragma unroll
    for (int i = 0; i < 8; i++) acc[i] = 0.f;
    for (int k = 0; k < 128; k++) {
        float w = W[k * 128 + j];
        #pragma unroll
        for (int i = 0; i < 8; i++) acc[i] += xs[(rr + 2 * i) * 128 + k] * w;
    }
    // attention dots: per wave, 8 rows x (r,c) pair for one head.
    // wave w: lanes carry channel = lane; head = (t>>6)&1; rows rr+2i.
    int lane = t & 63;
    int head = (t >> 6) & 1;
    float wr = attn0[head * 128 + lane];
    float wc = attn0[head * 128 + 64 + lane];
    #pragma unroll
    for (int i = 0; i < 8; i++) {
        float rs = bsum64(acc[i] * wr);
        float cs = bsum64(acc[i] * wc);
        if (lane == 0) {
            int n = n0 + rr + 2 * i;
            ar[n * 2 + head] = rs;
            ac[n * 2 + head] = cs;
        }
    }
    // pack h0 -> bf16x2 via LDS staging (xs reused)
    __syncthreads();
    #pragma unroll
    for (int i = 0; i < 8; i++) xs[(rr + 2 * i) * 128 + j] = acc[i];
    __syncthreads();
    int r = t >> 4;               // 0..15
    int cb = (t & 15) * 4;        // channel base 0..60
    uint4 u;
    u.x = packbf2(xs[r * 128 + cb + 0], xs[r * 128 + 64 + cb + 0]);
    u.y = packbf2(xs[r * 128 + cb + 1], xs[r * 128 + 64 + cb + 1]);
    u.z = packbf2(xs[r * 128 + cb + 2], xs[r * 128 + 64 + cb + 2]);
    u.w = packbf2(xs[r * 128 + cb + 3], xs[r * 128 + 64 + cb + 3]);
    *(uint4*)(h0b + (n0 + r) * 64 + cb) = u;
}

// ---- layer 0 edge work: softmax weights (no max-subtract) + aggregation
//      + relu + W1 transform -> h1[N,2].  One wave per node. ----
__global__ __launch_bounds__(256) void k_l0edge(const int* __restrict__ rowptr,
                                                const int* __restrict__ ecol,
                                                const float* __restrict__ ar,
                                                const float* __restrict__ ac,
                                                const unsigned* __restrict__ h0b,
                                                const float* __restrict__ W1,
                                                float* __restrict__ h1) {
    int w = threadIdx.x >> 6, lane = threadIdx.x & 63;
    int n = blockIdx.x * 4 + w;
    if (n >= NNODES) return;
    int beg = rowptr[n];
    int deg = rowptr[n + 1] - beg;
    float arn0 = ar[n * 2], arn1 = ar[n * 2 + 1];
    int esub = lane >> 4;          // which of 4 edges in flight
    int c16 = lane & 15;           // channel group (4 channels)
    float accA[4] = {0.f, 0.f, 0.f, 0.f};   // head 0
    float accB[4] = {0.f, 0.f, 0.f, 0.f};   // head 1
    float s0t = 0.f, s1t = 0.f;
    for (int wb = 0; wb < deg; wb += 64) {
        int cnt = deg - wb; if (cnt > 64) cnt = 64;
        // phase 1: lane = edge; compute p = exp(lrelu(a)) in-register
        float p0 = 0.f, p1 = 0.f; int colr = 0;
        if (lane < cnt) {
            colr = ecol[beg + wb + lane];
            float2 acv = ((const float2*)ac)[colr];
            float a0 = arn0 + acv.x, a1 = arn1 + acv.y;
            a0 = a0 > 0.f ? a0 : 0.2f * a0;
            a1 = a1 > 0.f ? a1 : 0.2f * a1;
            p0 = __expf(a0); p1 = __expf(a1);
            s0t += p0; s1t += p1;
        }
        // phase 2: 4 edges x 16 channel-groups; p/col via wave shuffle broadcast
        int tmax = (cnt + 3) >> 2;
        for (int tt = 0; tt < tmax; tt++) {
            int i4 = tt * 4 + esub;
            int colx = __shfl(colr, i4, 64);
            float q0 = __shfl(p0, i4, 64);
            float q1 = __shfl(p1, i4, 64);
            if (i4 < cnt) {
                const uint4 u = *(const uint4*)(h0b + colx * 64 + c16 * 4);
                accA[0] += q0 * bflo(u.x); accB[0] += q1 * bfhi(u.x);
                accA[1] += q0 * bflo(u.y); accB[1] += q1 * bfhi(u.y);
                accA[2] += q0 * bflo(u.z); accB[2] += q1 * bfhi(u.z);
                accA[3] += q0 * bflo(u.w); accB[3] += q1 * bfhi(u.w);
            }
        }
    }
    float s0 = bsum64(s0t), s1 = bsum64(s1t);
    // reduce over the 4 edge-slots (lane bits 4,5)
    #pragma unroll
    for (int jj = 0; jj < 4; jj++) {
        accA[jj] += __shfl_xor(accA[jj], 16, 64);
        accA[jj] += __shfl_xor(accA[jj], 32, 64);
        accB[jj] += __shfl_xor(accB[jj], 16, 64);
        accB[jj] += __shfl_xor(accB[jj], 32, 64);
    }
    float si0 = deg ? 0.5f / s0 : 0.f;
    float si1 = deg ? 0.5f / s1 : 0.f;
    float pA = 0.f, pB = 0.f;
    #pragma unroll
    for (int jj = 0; jj < 4; jj++) {
        float o = si0 * accA[jj] + si1 * accB[jj];
        o = o > 0.f ? o : 0.f;   // relu
        float2 wv = ((const float2*)W1)[c16 * 4 + jj];
        pA += o * wv.x; pB += o * wv.y;
    }
    // reduce over channel groups (lane bits 0-3)
    #pragma unroll
    for (int off = 1; off < 16; off <<= 1) {
        pA += __shfl_xor(pA, off, 64);
        pB += __shfl_xor(pB, off, 64);
    }
    if (lane == 0) { h1[n * 2] = pA; h1[n * 2 + 1] = pB; }
}

// ---- layer 1 fused: wave per node, lane = edge, plain (no-max) softmax ----
__global__ __launch_bounds__(256) void k_fused1(const int* __restrict__ rowptr,
                                                const int* __restrict__ ecol,
                                                const float* __restrict__ h1,
                                                const float* __restrict__ attn1,
                                                float* __restrict__ dout) {
    int w = threadIdx.x >> 6, lane = threadIdx.x & 63;
    int n = blockIdx.x * 4 + w;
    if (n >= NNODES) return;
    int beg = rowptr[n], end = rowptr[n + 1];
    if (beg == end) { if (lane == 0) dout[n] = 0.f; return; }
    float w01 = attn1[1], w11 = attn1[3];
    float base0 = attn1[0] * h1[n * 2];
    float base1 = attn1[2] * h1[n * 2 + 1];
    float s0 = 0.f, s1 = 0.f, acc0 = 0.f, acc1 = 0.f;
    for (int i = beg + lane; i < end; i += 64) {
        int col = ecol[i];
        float2 v = ((const float2*)h1)[col];
        float a0 = base0 + w01 * v.x;
        float a1 = base1 + w11 * v.y;
        a0 = a0 > 0.f ? a0 : 0.2f * a0;
        a1 = a1 > 0.f ? a1 : 0.2f * a1;
        float p0 = __expf(a0), p1 = __expf(a1);
        s0 += p0; acc0 += p0 * v.x;
        s1 += p1; acc1 += p1 * v.y;
    }
    s0 = bsum64(s0); s1 = bsum64(s1);
    acc0 = bsum64(acc0); acc1 = bsum64(acc1);
    if (lane == 0) dout[n] = 0.5f * (acc0 / s0 + acc1 / s1);
}

extern "C" void kernel_launch(void* const* d_in, const int* in_sizes, int n_in,
                              void* d_out, int out_size, void* d_ws, size_t ws_size,
                              hipStream_t stream) {
    const float* x     = (const float*)d_in[0];
    const int*   ei    = (const int*)d_in[1];
    const float* W0    = (const float*)d_in[2];
    const float* attn0 = (const float*)d_in[3];
    const float* W1    = (const float*)d_in[4];
    const float* attn1 = (const float*)d_in[5];
    float* dout = (float*)d_out;

    float* ws = (float*)d_ws;
    float*    ar     = ws;                           // N*2
    float*    ac     = ar + NNODES * 2;              // N*2
    float*    h1     = ac + NNODES * 2;              // N*2
    unsigned* h0b    = (unsigned*)(h1 + NNODES * 2); // N*64
    int*      deg    = (int*)(h0b + NNODES * 64);    // N
    int*      rowptr = deg + NNODES;                 // N+1
    int*      erank  = rowptr + NNODES + 1;          // E
    int*      bsum   = erank + NEDGES;               // SCAN_NB
    int*      boff   = bsum + SCAN_NB;               // SCAN_NB
    int*      ecol   = boff + SCAN_NB;               // E

    // CSR build
    k_zero<<<(NNODES + 255) / 256, 256, 0, stream>>>(deg);
    k_hist<<<(NEDGES + 255) / 256, 256, 0, stream>>>(ei, deg, erank);
    k_scan1<<<SCAN_NB, 256, 0, stream>>>(deg, rowptr, bsum);
    k_scan2<<<1, 256, 0, stream>>>(bsum, boff);
    k_scan3<<<SCAN_NB, 256, 0, stream>>>(rowptr, boff);
    k_scatter<<<(NEDGES + 255) / 256, 256, 0, stream>>>(ei, rowptr, erank, ecol);

    // layer 0
    k_l0node<<<NNODES / 16, 256, 0, stream>>>(x, W0, attn0, ar, ac, h0b);
    k_l0edge<<<(NNODES + 3) / 4, 256, 0, stream>>>(rowptr, ecol, ar, ac, h0b, W1, h1);

    // layer 1
    k_fused1<<<(NNODES + 3) / 4, 256, 0, stream>>>(rowptr, ecol, h1, attn1, dout);
}

// Round 7
// 152.313 us; speedup vs baseline: 3.0236x; 1.0689x over previous
//
#include <hip/hip_runtime.h>
#include <math.h>

#define NNODES 50000
#define NEDGES 800000
#define SCAN_NB ((NNODES + 255) / 256)   // 196

// butterfly reductions: result valid in ALL lanes
__device__ inline float bsum64(float v) {
    #pragma unroll
    for (int off = 1; off < 64; off <<= 1) v += __shfl_xor(v, off, 64);
    return v;
}

// pack two f32 -> 2x bf16 (RNE) in one uint
__device__ inline unsigned packbf2(float a, float b) {
    unsigned ua = __float_as_uint(a);
    unsigned ub = __float_as_uint(b);
    ua = (ua + 0x7fffu + ((ua >> 16) & 1u)) >> 16;
    ub = (ub + 0x7fffu + ((ub >> 16) & 1u)) >> 16;
    return ua | (ub << 16);
}
__device__ inline float bflo(unsigned u) { return __uint_as_float(u << 16); }
__device__ inline float bfhi(unsigned u) { return __uint_as_float(u & 0xffff0000u); }

// ---- zero the degree counters ----
__global__ void k_zero(int* __restrict__ deg) {
    int i = blockIdx.x * blockDim.x + threadIdx.x;
    if (i < NNODES) deg[i] = 0;
}

// ---- CSR build: histogram + per-edge local rank ----
__global__ __launch_bounds__(256) void k_hist(const int* __restrict__ ei,
                                              int* __restrict__ deg,
                                              int* __restrict__ erank) {
    int e = blockIdx.x * blockDim.x + threadIdx.x;
    if (e >= NEDGES) return;
    erank[e] = atomicAdd(&deg[ei[e]], 1);
}

// ---- scan pass 1 ----
__global__ __launch_bounds__(256) void k_scan1(const int* __restrict__ deg,
                                               int* __restrict__ rowptr,
                                               int* __restrict__ bsum) {
    __shared__ int sh[256];
    int t = threadIdx.x;
    int idx = blockIdx.x * 256 + t;
    int v = (idx < NNODES) ? deg[idx] : 0;
    sh[t] = v;
    __syncthreads();
    #pragma unroll
    for (int off = 1; off < 256; off <<= 1) {
        int u = (t >= off) ? sh[t - off] : 0;
        __syncthreads();
        sh[t] += u;
        __syncthreads();
    }
    if (idx < NNODES) rowptr[idx] = sh[t] - v;
    if (t == 255) bsum[blockIdx.x] = sh[255];
}

// ---- scan pass 2 ----
__global__ __launch_bounds__(256) void k_scan2(const int* __restrict__ bsum,
                                               int* __restrict__ boff) {
    __shared__ int sh[256];
    int t = threadIdx.x;
    int v = (t < SCAN_NB) ? bsum[t] : 0;
    sh[t] = v;
    __syncthreads();
    #pragma unroll
    for (int off = 1; off < 256; off <<= 1) {
        int u = (t >= off) ? sh[t - off] : 0;
        __syncthreads();
        sh[t] += u;
        __syncthreads();
    }
    if (t < SCAN_NB) boff[t] = sh[t] - v;
}

// ---- scan pass 3 ----
__global__ __launch_bounds__(256) void k_scan3(int* __restrict__ rowptr,
                                               const int* __restrict__ boff) {
    int idx = blockIdx.x * 256 + threadIdx.x;
    if (idx < NNODES) rowptr[idx] += boff[blockIdx.x];
    if (idx == 0) rowptr[NNODES] = NEDGES;
}

// ---- CSR build: scatter (no atomic) ----
__global__ __launch_bounds__(256) void k_scatter(const int* __restrict__ ei,
                                                 const int* __restrict__ rowptr,
                                                 const int* __restrict__ erank,
                                                 int* __restrict__ ecol) {
    int e = blockIdx.x * blockDim.x + threadIdx.x;
    if (e >= NEDGES) return;
    int row = ei[e], col = ei[NEDGES + e];
    ecol[rowptr[row] + erank[e]] = col;
}

// ---- layer 0 node work: register-blocked fp32 GEMM (4x4/thread) + attn dots + bf16 pack ----
// 32 rows per 256-thread block; thread (rg=t>>5, jg=t&31) owns rows rg*4..+3, cols jg*4..+3
__global__ __launch_bounds__(256) void k_l0node(const float* __restrict__ x,
                                                const float* __restrict__ W,
                                                const float* __restrict__ attn0,
                                                float* __restrict__ ar,
                                                float* __restrict__ ac,
                                                unsigned* __restrict__ h0b) {
    __shared__ float xs[32 * 128];   // 16 KB
    int n0 = blockIdx.x * 32;
    int t = threadIdx.x;
    // stage x (f32, coalesced float4); OOB rows -> 0
    for (int i = t; i < 32 * 32; i += 256) {
        int r = i >> 5, c4 = i & 31;
        int n = n0 + r;
        float4 v = (n < NNODES) ? *(const float4*)&x[n * 128 + c4 * 4]
                                : make_float4(0.f, 0.f, 0.f, 0.f);
        *(float4*)&xs[r * 128 + c4 * 4] = v;
    }
    __syncthreads();
    int rg = t >> 5;     // 0..7
    int jg = t & 31;     // 0..31  (col j = jg*4+jj; head = jg>>4; ch = (jg&15)*4+jj)
    float acc[4][4];
    #pragma unroll
    for (int i = 0; i < 4; i++)
        #pragma unroll
        for (int j = 0; j < 4; j++) acc[i][j] = 0.f;

    for (int k = 0; k < 128; k += 4) {
        float a[4][4], b[4][4];
        #pragma unroll
        for (int rr = 0; rr < 4; rr++)
            *(float4*)&a[rr][0] = *(const float4*)&xs[(rg * 4 + rr) * 128 + k];  // broadcast read
        #pragma unroll
        for (int kk = 0; kk < 4; kk++)
            *(float4*)&b[kk][0] = *(const float4*)&W[(k + kk) * 128 + jg * 4];   // L2-resident
        #pragma unroll
        for (int kk = 0; kk < 4; kk++)
            #pragma unroll
            for (int rr = 0; rr < 4; rr++)
                #pragma unroll
                for (int jj = 0; jj < 4; jj++)
                    acc[rr][jj] += a[rr][kk] * b[kk][jj];
    }

    // attention dots: per-head partial over this thread's 4 cols, butterfly over the 16-lane group
    int head = jg >> 4;
    const float4 wr4 = *(const float4*)&attn0[head * 128 + (jg & 15) * 4];
    const float4 wc4 = *(const float4*)&attn0[head * 128 + 64 + (jg & 15) * 4];
    #pragma unroll
    for (int rr = 0; rr < 4; rr++) {
        float pr = acc[rr][0] * wr4.x + acc[rr][1] * wr4.y + acc[rr][2] * wr4.z + acc[rr][3] * wr4.w;
        float pc = acc[rr][0] * wc4.x + acc[rr][1] * wc4.y + acc[rr][2] * wc4.z + acc[rr][3] * wc4.w;
        #pragma unroll
        for (int off = 1; off < 16; off <<= 1) {
            pr += __shfl_xor(pr, off, 64);
            pc += __shfl_xor(pc, off, 64);
        }
        int n = n0 + rg * 4 + rr;
        if ((t & 15) == 0 && n < NNODES) {
            ar[n * 2 + head] = pr;
            ac[n * 2 + head] = pc;
        }
    }

    // bf16 pack via LDS re-stage
    __syncthreads();
    #pragma unroll
    for (int rr = 0; rr < 4; rr++)
        *(float4*)&xs[(rg * 4 + rr) * 128 + jg * 4] = *(float4*)&acc[rr][0];
    __syncthreads();
    for (int i = t; i < 32 * 16; i += 256) {
        int r = i >> 4, cb = (i & 15) * 4;
        int n = n0 + r;
        if (n >= NNODES) break;
        uint4 u;
        u.x = packbf2(xs[r * 128 + cb + 0], xs[r * 128 + 64 + cb + 0]);
        u.y = packbf2(xs[r * 128 + cb + 1], xs[r * 128 + 64 + cb + 1]);
        u.z = packbf2(xs[r * 128 + cb + 2], xs[r * 128 + 64 + cb + 2]);
        u.w = packbf2(xs[r * 128 + cb + 3], xs[r * 128 + 64 + cb + 3]);
        *(uint4*)(h0b + n * 64 + cb) = u;
    }
}

// ---- layer 0 edge work: softmax weights (no max-subtract) + aggregation
//      + relu + W1 transform -> h1[N,2].  One wave per node. ----
__global__ __launch_bounds__(256) void k_l0edge(const int* __restrict__ rowptr,
                                                const int* __restrict__ ecol,
                                                const float* __restrict__ ar,
                                                const float* __restrict__ ac,
                                                const unsigned* __restrict__ h0b,
                                                const float* __restrict__ W1,
                                                float* __restrict__ h1) {
    int w = threadIdx.x >> 6, lane = threadIdx.x & 63;
    int n = blockIdx.x * 4 + w;
    if (n >= NNODES) return;
    int beg = rowptr[n];
    int deg = rowptr[n + 1] - beg;
    float arn0 = ar[n * 2], arn1 = ar[n * 2 + 1];
    int esub = lane >> 4;          // which of 4 edges in flight
    int c16 = lane & 15;           // channel group (4 channels)
    float accA[4] = {0.f, 0.f, 0.f, 0.f};   // head 0
    float accB[4] = {0.f, 0.f, 0.f, 0.f};   // head 1
    float s0t = 0.f, s1t = 0.f;
    for (int wb = 0; wb < deg; wb += 64) {
        int cnt = deg - wb; if (cnt > 64) cnt = 64;
        float p0 = 0.f, p1 = 0.f; int colr = 0;
        if (lane < cnt) {
            colr = ecol[beg + wb + lane];
            float2 acv = ((const float2*)ac)[colr];
            float a0 = arn0 + acv.x, a1 = arn1 + acv.y;
            a0 = a0 > 0.f ? a0 : 0.2f * a0;
            a1 = a1 > 0.f ? a1 : 0.2f * a1;
            p0 = __expf(a0); p1 = __expf(a1);
            s0t += p0; s1t += p1;
        }
        int tmax = (cnt + 3) >> 2;
        for (int tt = 0; tt < tmax; tt++) {
            int i4 = tt * 4 + esub;
            int colx = __shfl(colr, i4, 64);
            float q0 = __shfl(p0, i4, 64);
            float q1 = __shfl(p1, i4, 64);
            if (i4 < cnt) {
                const uint4 u = *(const uint4*)(h0b + colx * 64 + c16 * 4);
                accA[0] += q0 * bflo(u.x); accB[0] += q1 * bfhi(u.x);
                accA[1] += q0 * bflo(u.y); accB[1] += q1 * bfhi(u.y);
                accA[2] += q0 * bflo(u.z); accB[2] += q1 * bfhi(u.z);
                accA[3] += q0 * bflo(u.w); accB[3] += q1 * bfhi(u.w);
            }
        }
    }
    float s0 = bsum64(s0t), s1 = bsum64(s1t);
    #pragma unroll
    for (int jj = 0; jj < 4; jj++) {
        accA[jj] += __shfl_xor(accA[jj], 16, 64);
        accA[jj] += __shfl_xor(accA[jj], 32, 64);
        accB[jj] += __shfl_xor(accB[jj], 16, 64);
        accB[jj] += __shfl_xor(accB[jj], 32, 64);
    }
    float si0 = deg ? 0.5f / s0 : 0.f;
    float si1 = deg ? 0.5f / s1 : 0.f;
    float pA = 0.f, pB = 0.f;
    #pragma unroll
    for (int jj = 0; jj < 4; jj++) {
        float o = si0 * accA[jj] + si1 * accB[jj];
        o = o > 0.f ? o : 0.f;   // relu
        float2 wv = ((const float2*)W1)[c16 * 4 + jj];
        pA += o * wv.x; pB += o * wv.y;
    }
    #pragma unroll
    for (int off = 1; off < 16; off <<= 1) {
        pA += __shfl_xor(pA, off, 64);
        pB += __shfl_xor(pB, off, 64);
    }
    if (lane == 0) { h1[n * 2] = pA; h1[n * 2 + 1] = pB; }
}

// ---- layer 1 fused: wave per node, lane = edge, plain (no-max) softmax ----
__global__ __launch_bounds__(256) void k_fused1(const int* __restrict__ rowptr,
                                                const int* __restrict__ ecol,
                                                const float* __restrict__ h1,
                                                const float* __restrict__ attn1,
                                                float* __restrict__ dout) {
    int w = threadIdx.x >> 6, lane = threadIdx.x & 63;
    int n = blockIdx.x * 4 + w;
    if (n >= NNODES) return;
    int beg = rowptr[n], end = rowptr[n + 1];
    if (beg == end) { if (lane == 0) dout[n] = 0.f; return; }
    float w01 = attn1[1], w11 = attn1[3];
    float base0 = attn1[0] * h1[n * 2];
    float base1 = attn1[2] * h1[n * 2 + 1];
    float s0 = 0.f, s1 = 0.f, acc0 = 0.f, acc1 = 0.f;
    for (int i = beg + lane; i < end; i += 64) {
        int col = ecol[i];
        float2 v = ((const float2*)h1)[col];
        float a0 = base0 + w01 * v.x;
        float a1 = base1 + w11 * v.y;
        a0 = a0 > 0.f ? a0 : 0.2f * a0;
        a1 = a1 > 0.f ? a1 : 0.2f * a1;
        float p0 = __expf(a0), p1 = __expf(a1);
        s0 += p0; acc0 += p0 * v.x;
        s1 += p1; acc1 += p1 * v.y;
    }
    s0 = bsum64(s0); s1 = bsum64(s1);
    acc0 = bsum64(acc0); acc1 = bsum64(acc1);
    if (lane == 0) dout[n] = 0.5f * (acc0 / s0 + acc1 / s1);
}

extern "C" void kernel_launch(void* const* d_in, const int* in_sizes, int n_in,
                              void* d_out, int out_size, void* d_ws, size_t ws_size,
                              hipStream_t stream) {
    const float* x     = (const float*)d_in[0];
    const int*   ei    = (const int*)d_in[1];
    const float* W0    = (const float*)d_in[2];
    const float* attn0 = (const float*)d_in[3];
    const float* W1    = (const float*)d_in[4];
    const float* attn1 = (const float*)d_in[5];
    float* dout = (float*)d_out;

    float* ws = (float*)d_ws;
    float*    ar     = ws;                           // N*2
    float*    ac     = ar + NNODES * 2;              // N*2
    float*    h1     = ac + NNODES * 2;              // N*2
    unsigned* h0b    = (unsigned*)(h1 + NNODES * 2); // N*64
    int*      deg    = (int*)(h0b + NNODES * 64);    // N
    int*      rowptr = deg + NNODES;                 // N+1
    int*      erank  = rowptr + NNODES + 1;          // E
    int*      bsum   = erank + NEDGES;               // SCAN_NB
    int*      boff   = bsum + SCAN_NB;               // SCAN_NB
    int*      ecol   = boff + SCAN_NB;               // E

    // CSR build
    k_zero<<<(NNODES + 255) / 256, 256, 0, stream>>>(deg);
    k_hist<<<(NEDGES + 255) / 256, 256, 0, stream>>>(ei, deg, erank);
    k_scan1<<<SCAN_NB, 256, 0, stream>>>(deg, rowptr, bsum);
    k_scan2<<<1, 256, 0, stream>>>(bsum, boff);
    k_scan3<<<SCAN_NB, 256, 0, stream>>>(rowptr, boff);
    k_scatter<<<(NEDGES + 255) / 256, 256, 0, stream>>>(ei, rowptr, erank, ecol);

    // layer 0
    k_l0node<<<(NNODES + 31) / 32, 256, 0, stream>>>(x, W0, attn0, ar, ac, h0b);
    k_l0edge<<<(NNODES + 3) / 4, 256, 0, stream>>>(rowptr, ecol, ar, ac, h0b, W1, h1);

    // layer 1
    k_fused1<<<(NNODES + 3) / 4, 256, 0, stream>>>(rowptr, ecol, h1, attn1, dout);
}

// Round 8
// 150.283 us; speedup vs baseline: 3.0644x; 1.0135x over previous
//
#include <hip/hip_runtime.h>
#include <math.h>

#define NNODES 50000
#define NEDGES 800000
#define SCAN_NB ((NNODES + 255) / 256)   // 196
#define L0ROWS 64

// butterfly reductions: result valid in ALL lanes
__device__ inline float bsum64(float v) {
    #pragma unroll
    for (int off = 1; off < 64; off <<= 1) v += __shfl_xor(v, off, 64);
    return v;
}

// pack two f32 -> 2x bf16 (RNE) in one uint
__device__ inline unsigned packbf2(float a, float b) {
    unsigned ua = __float_as_uint(a);
    unsigned ub = __float_as_uint(b);
    ua = (ua + 0x7fffu + ((ua >> 16) & 1u)) >> 16;
    ub = (ub + 0x7fffu + ((ub >> 16) & 1u)) >> 16;
    return ua | (ub << 16);
}
__device__ inline float bflo(unsigned u) { return __uint_as_float(u << 16); }
__device__ inline float bfhi(unsigned u) { return __uint_as_float(u & 0xffff0000u); }

// ---- zero the degree counters ----
__global__ void k_zero(int* __restrict__ deg) {
    int i = blockIdx.x * blockDim.x + threadIdx.x;
    if (i < NNODES) deg[i] = 0;
}

// ---- CSR build: histogram + per-edge local rank ----
__global__ __launch_bounds__(256) void k_hist(const int* __restrict__ ei,
                                              int* __restrict__ deg,
                                              int* __restrict__ erank) {
    int e = blockIdx.x * blockDim.x + threadIdx.x;
    if (e >= NEDGES) return;
    erank[e] = atomicAdd(&deg[ei[e]], 1);
}

// ---- scan pass 1 ----
__global__ __launch_bounds__(256) void k_scan1(const int* __restrict__ deg,
                                               int* __restrict__ rowptr,
                                               int* __restrict__ bsum) {
    __shared__ int sh[256];
    int t = threadIdx.x;
    int idx = blockIdx.x * 256 + t;
    int v = (idx < NNODES) ? deg[idx] : 0;
    sh[t] = v;
    __syncthreads();
    #pragma unroll
    for (int off = 1; off < 256; off <<= 1) {
        int u = (t >= off) ? sh[t - off] : 0;
        __syncthreads();
        sh[t] += u;
        __syncthreads();
    }
    if (idx < NNODES) rowptr[idx] = sh[t] - v;
    if (t == 255) bsum[blockIdx.x] = sh[255];
}

// ---- scan pass 2 ----
__global__ __launch_bounds__(256) void k_scan2(const int* __restrict__ bsum,
                                               int* __restrict__ boff) {
    __shared__ int sh[256];
    int t = threadIdx.x;
    int v = (t < SCAN_NB) ? bsum[t] : 0;
    sh[t] = v;
    __syncthreads();
    #pragma unroll
    for (int off = 1; off < 256; off <<= 1) {
        int u = (t >= off) ? sh[t - off] : 0;
        __syncthreads();
        sh[t] += u;
        __syncthreads();
    }
    if (t < SCAN_NB) boff[t] = sh[t] - v;
}

// ---- scan pass 3 ----
__global__ __launch_bounds__(256) void k_scan3(int* __restrict__ rowptr,
                                               const int* __restrict__ boff) {
    int idx = blockIdx.x * 256 + threadIdx.x;
    if (idx < NNODES) rowptr[idx] += boff[blockIdx.x];
    if (idx == 0) rowptr[NNODES] = NEDGES;
}

// ---- CSR build: scatter (no atomic) ----
__global__ __launch_bounds__(256) void k_scatter(const int* __restrict__ ei,
                                                 const int* __restrict__ rowptr,
                                                 const int* __restrict__ erank,
                                                 int* __restrict__ ecol) {
    int e = blockIdx.x * blockDim.x + threadIdx.x;
    if (e >= NEDGES) return;
    int row = ei[e], col = ei[NEDGES + e];
    ecol[rowptr[row] + erank[e]] = col;
}

// ---- layer 0 node work: fp32 GEMM, 64 rows/block, 8x4 per thread, W prefetch ----
// thread (rg=t>>5, jg=t&31) owns rows rg*8..+7, cols jg*4..+3
__global__ __launch_bounds__(256) void k_l0node(const float* __restrict__ x,
                                                const float* __restrict__ W,
                                                const float* __restrict__ attn0,
                                                float* __restrict__ ar,
                                                float* __restrict__ ac,
                                                unsigned* __restrict__ h0b) {
    __shared__ float xs[L0ROWS * 128];   // 32 KB
    int n0 = blockIdx.x * L0ROWS;
    int t = threadIdx.x;
    // stage x (f32, coalesced float4); OOB rows -> 0
    for (int i = t; i < L0ROWS * 32; i += 256) {
        int r = i >> 5, c4 = i & 31;
        int n = n0 + r;
        float4 v = (n < NNODES) ? *(const float4*)&x[n * 128 + c4 * 4]
                                : make_float4(0.f, 0.f, 0.f, 0.f);
        *(float4*)&xs[r * 128 + c4 * 4] = v;
    }
    __syncthreads();
    int rg = t >> 5;     // 0..7  -> rows rg*8..+7
    int jg = t & 31;     // 0..31 -> cols jg*4..+3 (head = jg>>4)
    float acc[8][4];
    #pragma unroll
    for (int i = 0; i < 8; i++)
        #pragma unroll
        for (int j = 0; j < 4; j++) acc[i][j] = 0.f;

    // prefetch first W k-block into registers
    float4 bc[4];
    #pragma unroll
    for (int kk = 0; kk < 4; kk++)
        bc[kk] = *(const float4*)&W[kk * 128 + jg * 4];

    for (int k = 0; k < 128; k += 4) {
        float4 av[8];
        #pragma unroll
        for (int rr = 0; rr < 8; rr++)
            av[rr] = *(const float4*)&xs[(rg * 8 + rr) * 128 + k];   // broadcast, conflict-free
        // prefetch next W k-block (hidden under the 128 FMAs below)
        float4 bn[4];
        int k2 = (k + 4) & 127;
        #pragma unroll
        for (int kk = 0; kk < 4; kk++)
            bn[kk] = *(const float4*)&W[(k2 + kk) * 128 + jg * 4];
        #pragma unroll
        for (int kk = 0; kk < 4; kk++) {
            #pragma unroll
            for (int rr = 0; rr < 8; rr++) {
                float a = ((const float*)&av[rr])[kk];
                acc[rr][0] += a * bc[kk].x;
                acc[rr][1] += a * bc[kk].y;
                acc[rr][2] += a * bc[kk].z;
                acc[rr][3] += a * bc[kk].w;
            }
        }
        #pragma unroll
        for (int kk = 0; kk < 4; kk++) bc[kk] = bn[kk];
    }

    // attention dots: per-head partials over this thread's 4 cols, butterfly over 16-lane group
    int head = jg >> 4;
    const float4 wr4 = *(const float4*)&attn0[head * 128 + (jg & 15) * 4];
    const float4 wc4 = *(const float4*)&attn0[head * 128 + 64 + (jg & 15) * 4];
    #pragma unroll
    for (int rr = 0; rr < 8; rr++) {
        float pr = acc[rr][0] * wr4.x + acc[rr][1] * wr4.y + acc[rr][2] * wr4.z + acc[rr][3] * wr4.w;
        float pc = acc[rr][0] * wc4.x + acc[rr][1] * wc4.y + acc[rr][2] * wc4.z + acc[rr][3] * wc4.w;
        #pragma unroll
        for (int off = 1; off < 16; off <<= 1) {
            pr += __shfl_xor(pr, off, 64);
            pc += __shfl_xor(pc, off, 64);
        }
        int n = n0 + rg * 8 + rr;
        if ((t & 15) == 0 && n < NNODES) {
            ar[n * 2 + head] = pr;
            ac[n * 2 + head] = pc;
        }
    }

    // bf16 pack via LDS re-stage
    __syncthreads();
    #pragma unroll
    for (int rr = 0; rr < 8; rr++)
        *(float4*)&xs[(rg * 8 + rr) * 128 + jg * 4] = *(float4*)&acc[rr][0];
    __syncthreads();
    for (int i = t; i < L0ROWS * 16; i += 256) {
        int r = i >> 4, cb = (i & 15) * 4;
        int n = n0 + r;
        if (n < NNODES) {
            uint4 u;
            u.x = packbf2(xs[r * 128 + cb + 0], xs[r * 128 + 64 + cb + 0]);
            u.y = packbf2(xs[r * 128 + cb + 1], xs[r * 128 + 64 + cb + 1]);
            u.z = packbf2(xs[r * 128 + cb + 2], xs[r * 128 + 64 + cb + 2]);
            u.w = packbf2(xs[r * 128 + cb + 3], xs[r * 128 + 64 + cb + 3]);
            *(uint4*)(h0b + n * 64 + cb) = u;
        }
    }
}

// ---- layer 0 edge work: softmax weights (no max-subtract) + aggregation
//      + relu + W1 transform -> h1[N,2].  One wave per node. ----
__global__ __launch_bounds__(256) void k_l0edge(const int* __restrict__ rowptr,
                                                const int* __restrict__ ecol,
                                                const float* __restrict__ ar,
                                                const float* __restrict__ ac,
                                                const unsigned* __restrict__ h0b,
                                                const float* __restrict__ W1,
                                                float* __restrict__ h1) {
    int w = threadIdx.x >> 6, lane = threadIdx.x & 63;
    int n = blockIdx.x * 4 + w;
    if (n >= NNODES) return;
    int beg = rowptr[n];
    int deg = rowptr[n + 1] - beg;
    float arn0 = ar[n * 2], arn1 = ar[n * 2 + 1];
    int esub = lane >> 4;          // which of 4 edges in flight
    int c16 = lane & 15;           // channel group (4 channels)
    float accA[4] = {0.f, 0.f, 0.f, 0.f};   // head 0
    float accB[4] = {0.f, 0.f, 0.f, 0.f};   // head 1
    float s0t = 0.f, s1t = 0.f;
    for (int wb = 0; wb < deg; wb += 64) {
        int cnt = deg - wb; if (cnt > 64) cnt = 64;
        float p0 = 0.f, p1 = 0.f; int colr = 0;
        if (lane < cnt) {
            colr = ecol[beg + wb + lane];
            float2 acv = ((const float2*)ac)[colr];
            float a0 = arn0 + acv.x, a1 = arn1 + acv.y;
            a0 = a0 > 0.f ? a0 : 0.2f * a0;
            a1 = a1 > 0.f ? a1 : 0.2f * a1;
            p0 = __expf(a0); p1 = __expf(a1);
            s0t += p0; s1t += p1;
        }
        int tmax = (cnt + 3) >> 2;
        for (int tt = 0; tt < tmax; tt++) {
            int i4 = tt * 4 + esub;
            int colx = __shfl(colr, i4, 64);
            float q0 = __shfl(p0, i4, 64);
            float q1 = __shfl(p1, i4, 64);
            if (i4 < cnt) {
                const uint4 u = *(const uint4*)(h0b + colx * 64 + c16 * 4);
                accA[0] += q0 * bflo(u.x); accB[0] += q1 * bfhi(u.x);
                accA[1] += q0 * bflo(u.y); accB[1] += q1 * bfhi(u.y);
                accA[2] += q0 * bflo(u.z); accB[2] += q1 * bfhi(u.z);
                accA[3] += q0 * bflo(u.w); accB[3] += q1 * bfhi(u.w);
            }
        }
    }
    float s0 = bsum64(s0t), s1 = bsum64(s1t);
    #pragma unroll
    for (int jj = 0; jj < 4; jj++) {
        accA[jj] += __shfl_xor(accA[jj], 16, 64);
        accA[jj] += __shfl_xor(accA[jj], 32, 64);
        accB[jj] += __shfl_xor(accB[jj], 16, 64);
        accB[jj] += __shfl_xor(accB[jj], 32, 64);
    }
    float si0 = deg ? 0.5f / s0 : 0.f;
    float si1 = deg ? 0.5f / s1 : 0.f;
    float pA = 0.f, pB = 0.f;
    #pragma unroll
    for (int jj = 0; jj < 4; jj++) {
        float o = si0 * accA[jj] + si1 * accB[jj];
        o = o > 0.f ? o : 0.f;   // relu
        float2 wv = ((const float2*)W1)[c16 * 4 + jj];
        pA += o * wv.x; pB += o * wv.y;
    }
    #pragma unroll
    for (int off = 1; off < 16; off <<= 1) {
        pA += __shfl_xor(pA, off, 64);
        pB += __shfl_xor(pB, off, 64);
    }
    if (lane == 0) { h1[n * 2] = pA; h1[n * 2 + 1] = pB; }
}

// ---- layer 1 fused: wave per node, lane = edge, plain (no-max) softmax ----
__global__ __launch_bounds__(256) void k_fused1(const int* __restrict__ rowptr,
                                                const int* __restrict__ ecol,
                                                const float* __restrict__ h1,
                                                const float* __restrict__ attn1,
                                                float* __restrict__ dout) {
    int w = threadIdx.x >> 6, lane = threadIdx.x & 63;
    int n = blockIdx.x * 4 + w;
    if (n >= NNODES) return;
    int beg = rowptr[n], end = rowptr[n + 1];
    if (beg == end) { if (lane == 0) dout[n] = 0.f; return; }
    float w01 = attn1[1], w11 = attn1[3];
    float base0 = attn1[0] * h1[n * 2];
    float base1 = attn1[2] * h1[n * 2 + 1];
    float s0 = 0.f, s1 = 0.f, acc0 = 0.f, acc1 = 0.f;
    for (int i = beg + lane; i < end; i += 64) {
        int col = ecol[i];
        float2 v = ((const float2*)h1)[col];
        float a0 = base0 + w01 * v.x;
        float a1 = base1 + w11 * v.y;
        a0 = a0 > 0.f ? a0 : 0.2f * a0;
        a1 = a1 > 0.f ? a1 : 0.2f * a1;
        float p0 = __expf(a0), p1 = __expf(a1);
        s0 += p0; acc0 += p0 * v.x;
        s1 += p1; acc1 += p1 * v.y;
    }
    s0 = bsum64(s0); s1 = bsum64(s1);
    acc0 = bsum64(acc0); acc1 = bsum64(acc1);
    if (lane == 0) dout[n] = 0.5f * (acc0 / s0 + acc1 / s1);
}

extern "C" void kernel_launch(void* const* d_in, const int* in_sizes, int n_in,
                              void* d_out, int out_size, void* d_ws, size_t ws_size,
                              hipStream_t stream) {
    const float* x     = (const float*)d_in[0];
    const int*   ei    = (const int*)d_in[1];
    const float* W0    = (const float*)d_in[2];
    const float* attn0 = (const float*)d_in[3];
    const float* W1    = (const float*)d_in[4];
    const float* attn1 = (const float*)d_in[5];
    float* dout = (float*)d_out;

    float* ws = (float*)d_ws;
    float*    ar     = ws;                           // N*2
    float*    ac     = ar + NNODES * 2;              // N*2
    float*    h1     = ac + NNODES * 2;              // N*2
    unsigned* h0b    = (unsigned*)(h1 + NNODES * 2); // N*64
    int*      deg    = (int*)(h0b + NNODES * 64);    // N
    int*      rowptr = deg + NNODES;                 // N+1
    int*      erank  = rowptr + NNODES + 1;          // E
    int*      bsum   = erank + NEDGES;               // SCAN_NB
    int*      boff   = bsum + SCAN_NB;               // SCAN_NB
    int*      ecol   = boff + SCAN_NB;               // E

    // CSR build
    k_zero<<<(NNODES + 255) / 256, 256, 0, stream>>>(deg);
    k_hist<<<(NEDGES + 255) / 256, 256, 0, stream>>>(ei, deg, erank);
    k_scan1<<<SCAN_NB, 256, 0, stream>>>(deg, rowptr, bsum);
    k_scan2<<<1, 256, 0, stream>>>(bsum, boff);
    k_scan3<<<SCAN_NB, 256, 0, stream>>>(rowptr, boff);
    k_scatter<<<(NEDGES + 255) / 256, 256, 0, stream>>>(ei, rowptr, erank, ecol);

    // layer 0
    k_l0node<<<(NNODES + L0ROWS - 1) / L0ROWS, 256, 0, stream>>>(x, W0, attn0, ar, ac, h0b);
    k_l0edge<<<(NNODES + 3) / 4, 256, 0, stream>>>(rowptr, ecol, ar, ac, h0b, W1, h1);

    // layer 1
    k_fused1<<<(NNODES + 3) / 4, 256, 0, stream>>>(rowptr, ecol, h1, attn1, dout);
}